// Round 1
// baseline (1178.863 us; speedup 1.0000x reference)
//
#include <hip/hip_runtime.h>
#include <math.h>

#define N_NODES 50000
#define N_EDGES 600000
#define F_INPUT 128
#define HCDIM 256
#define NGRAPH 64
#define NCLS 3

// ============================ CSR build ============================
__global__ void hist_kernel(const int* __restrict__ ei, int* __restrict__ deg) {
    int i = blockIdx.x * 256 + threadIdx.x;
    int total = N_EDGES + N_NODES;
    if (i >= total) return;
    int d = (i < N_EDGES) ? ei[N_EDGES + i] : (i - N_EDGES);
    atomicAdd(&deg[d], 1);
}

__global__ void scan_kernel(const int* __restrict__ deg, int* __restrict__ rowptr,
                            int* __restrict__ cursor) {
    __shared__ int wtot[16];
    __shared__ int carry_s;
    int t = threadIdx.x, lane = t & 63, wid = t >> 6;
    if (t == 0) carry_s = 0;
    __syncthreads();
    for (int base = 0; base < N_NODES; base += 1024) {
        int i = base + t;
        int v = (i < N_NODES) ? deg[i] : 0;
        int x = v;
        #pragma unroll
        for (int off = 1; off < 64; off <<= 1) {
            int y = __shfl_up(x, off, 64);
            if (lane >= off) x += y;
        }
        if (lane == 63) wtot[wid] = x;
        __syncthreads();
        if (wid == 0) {
            int wv = (lane < 16) ? wtot[lane] : 0;
            #pragma unroll
            for (int off = 1; off < 16; off <<= 1) {
                int y = __shfl_up(wv, off, 64);
                if (lane >= off) wv += y;
            }
            if (lane < 16) wtot[lane] = wv;
        }
        __syncthreads();
        int waveoff = (wid > 0) ? wtot[wid - 1] : 0;
        int carry = carry_s;
        if (i < N_NODES) {
            int ex = carry + waveoff + x - v;
            rowptr[i] = ex;
            cursor[i] = ex;
        }
        __syncthreads();
        if (t == 0) carry_s = carry + wtot[15];
        __syncthreads();
    }
    if (t == 0) rowptr[N_NODES] = carry_s;
}

__global__ void fill_kernel(const int* __restrict__ ei, int* __restrict__ cursor,
                            int* __restrict__ colx) {
    int i = blockIdx.x * 256 + threadIdx.x;
    int total = N_EDGES + N_NODES;
    if (i >= total) return;
    int s, d;
    if (i < N_EDGES) { s = ei[i]; d = ei[N_EDGES + i]; }
    else             { s = i - N_EDGES; d = s; }
    int pos = atomicAdd(&cursor[d], 1);
    colx[pos] = s;
}

// ============================ Dual GEMM: xl = act(X)@Wl+bl, xr = act(X)@Wr+br ============================
// 64x64 tile, BK=16, 256 threads, 4x4 microtile per thread. fp32 vector ALU (no fp32 MFMA on CDNA4).
__global__ __launch_bounds__(256) void gemm_xlxr(
    const float* __restrict__ X, int K, int relu_in,
    const float* __restrict__ Wl, const float* __restrict__ bl,
    const float* __restrict__ Wr, const float* __restrict__ br,
    float* __restrict__ xl, float* __restrict__ xr)
{
    __shared__ float As[16][68];   // [k][m], padded stride 68 (272B, 16B-aligned)
    __shared__ float Bs[16][64];   // [k][n]
    int by = blockIdx.y;
    const float* W; const float* bvec; float* out; int col0;
    if (by < 4) { W = Wl; bvec = bl; out = xl; col0 = by * 64; }
    else        { W = Wr; bvec = br; out = xr; col0 = (by - 4) * 64; }
    int row0 = blockIdx.x * 64;
    int tid = threadIdx.x;
    int ty = tid >> 4, tx = tid & 15;
    float acc[4][4] = {{0.f}};

    int ra = tid >> 2;            // 0..63  A-load row
    int ka = (tid & 3) * 4;       // 0,4,8,12
    int kb = tid >> 4;            // 0..15  B-load k
    int cb = (tid & 15) * 4;      // 0..60

    for (int k0 = 0; k0 < K; k0 += 16) {
        int gr = row0 + ra;
        float4 a4 = make_float4(0.f, 0.f, 0.f, 0.f);
        if (gr < N_NODES) a4 = *(const float4*)&X[(size_t)gr * K + k0 + ka];
        if (relu_in) {
            a4.x = fmaxf(a4.x, 0.f); a4.y = fmaxf(a4.y, 0.f);
            a4.z = fmaxf(a4.z, 0.f); a4.w = fmaxf(a4.w, 0.f);
        }
        As[ka + 0][ra] = a4.x; As[ka + 1][ra] = a4.y;
        As[ka + 2][ra] = a4.z; As[ka + 3][ra] = a4.w;
        float4 b4 = *(const float4*)&W[(size_t)(k0 + kb) * HCDIM + col0 + cb];
        *(float4*)&Bs[kb][cb] = b4;
        __syncthreads();
        #pragma unroll
        for (int kk = 0; kk < 16; ++kk) {
            float4 a = *(const float4*)&As[kk][ty * 4];
            float4 b = *(const float4*)&Bs[kk][tx * 4];
            acc[0][0] += a.x * b.x; acc[0][1] += a.x * b.y; acc[0][2] += a.x * b.z; acc[0][3] += a.x * b.w;
            acc[1][0] += a.y * b.x; acc[1][1] += a.y * b.y; acc[1][2] += a.y * b.z; acc[1][3] += a.y * b.w;
            acc[2][0] += a.z * b.x; acc[2][1] += a.z * b.y; acc[2][2] += a.z * b.z; acc[2][3] += a.z * b.w;
            acc[3][0] += a.w * b.x; acc[3][1] += a.w * b.y; acc[3][2] += a.w * b.z; acc[3][3] += a.w * b.w;
        }
        __syncthreads();
    }
    float4 bb = *(const float4*)&bvec[col0 + tx * 4];
    #pragma unroll
    for (int i = 0; i < 4; ++i) {
        int gr = row0 + ty * 4 + i;
        if (gr < N_NODES) {
            float4 o;
            o.x = acc[i][0] + bb.x; o.y = acc[i][1] + bb.y;
            o.z = acc[i][2] + bb.z; o.w = acc[i][3] + bb.w;
            *(float4*)&out[(size_t)gr * HCDIM + col0 + tx * 4] = o;
        }
    }
}

// ============================ Edge phase: one wave per dst node, online softmax ============================
// lane l: head h = l>>4, channels c0 = (l&15)*4 .. +3 (float4).
__global__ __launch_bounds__(256) void gat_edge(
    const float* __restrict__ xl, const float* __restrict__ xr,
    const float* __restrict__ att, const float* __restrict__ bias,
    const int* __restrict__ rowptr, const int* __restrict__ colx,
    float* __restrict__ out)
{
    int wave = threadIdx.x >> 6;
    int lane = threadIdx.x & 63;
    int node = blockIdx.x * 4 + wave;
    if (node >= N_NODES) return;
    int base = lane * 4;
    float4 xr4 = *(const float4*)&xr[(size_t)node * HCDIM + base];
    float4 at4 = *(const float4*)&att[base];
    int e0 = rowptr[node], e1 = rowptr[node + 1];
    float m = -INFINITY, denom = 0.f;
    float4 acc = make_float4(0.f, 0.f, 0.f, 0.f);
    for (int e = e0; e < e1; ++e) {
        int s = colx[e];
        float4 xs = *(const float4*)&xl[(size_t)s * HCDIM + base];
        float4 v;
        v.x = xs.x + xr4.x; v.y = xs.y + xr4.y; v.z = xs.z + xr4.z; v.w = xs.w + xr4.w;
        // leaky_relu(0.2)
        v.x = fmaxf(v.x, 0.f) + 0.2f * fminf(v.x, 0.f);
        v.y = fmaxf(v.y, 0.f) + 0.2f * fminf(v.y, 0.f);
        v.z = fmaxf(v.z, 0.f) + 0.2f * fminf(v.z, 0.f);
        v.w = fmaxf(v.w, 0.f) + 0.2f * fminf(v.w, 0.f);
        float p = at4.x * v.x + at4.y * v.y + at4.z * v.z + at4.w * v.w;
        // reduce over the 16 lanes of this head group -> per-head score
        p += __shfl_xor(p, 1, 64);
        p += __shfl_xor(p, 2, 64);
        p += __shfl_xor(p, 4, 64);
        p += __shfl_xor(p, 8, 64);
        // online softmax update
        float mn = fmaxf(m, p);
        float corr = __expf(m - mn);
        float w = __expf(p - mn);
        acc.x = acc.x * corr + w * xs.x;
        acc.y = acc.y * corr + w * xs.y;
        acc.z = acc.z * corr + w * xs.z;
        acc.w = acc.w * corr + w * xs.w;
        denom = denom * corr + w;
        m = mn;
    }
    float inv = 1.f / denom;
    float4 b4 = *(const float4*)&bias[base];
    float4 o;
    o.x = acc.x * inv + b4.x; o.y = acc.y * inv + b4.y;
    o.z = acc.z * inv + b4.z; o.w = acc.w * inv + b4.w;
    *(float4*)&out[(size_t)node * HCDIM + base] = o;
}

// ============================ Pooling ============================
__global__ void boundary_kernel(const int* __restrict__ batch, int* __restrict__ startg,
                                int* __restrict__ endg) {
    int i = blockIdx.x * 256 + threadIdx.x;
    if (i >= N_NODES) return;
    int g = batch[i];
    if (i == 0 || batch[i - 1] != g) startg[g] = i;
    if (i == N_NODES - 1 || batch[i + 1] != g) endg[g] = i + 1;
}

__global__ __launch_bounds__(256) void pool_kernel(
    const float* __restrict__ h, const int* __restrict__ startg,
    const int* __restrict__ endg, float* __restrict__ p)
{
    __shared__ float4 sS[4][64];
    __shared__ float4 sM[4][64];
    int g = blockIdx.x;
    int lane = threadIdx.x & 63;
    int sub = threadIdx.x >> 6;
    int c0 = lane * 4;
    int s = startg[g], e = endg[g];
    float4 sum = make_float4(0.f, 0.f, 0.f, 0.f);
    float4 mx = make_float4(-INFINITY, -INFINITY, -INFINITY, -INFINITY);
    for (int i = s + sub; i < e; i += 4) {
        float4 v = *(const float4*)&h[(size_t)i * HCDIM + c0];
        sum.x += v.x; sum.y += v.y; sum.z += v.z; sum.w += v.w;
        mx.x = fmaxf(mx.x, v.x); mx.y = fmaxf(mx.y, v.y);
        mx.z = fmaxf(mx.z, v.z); mx.w = fmaxf(mx.w, v.w);
    }
    sS[sub][lane] = sum; sM[sub][lane] = mx;
    __syncthreads();
    if (sub == 0) {
        #pragma unroll
        for (int j = 1; j < 4; ++j) {
            float4 a = sS[j][lane], b = sM[j][lane];
            sum.x += a.x; sum.y += a.y; sum.z += a.z; sum.w += a.w;
            mx.x = fmaxf(mx.x, b.x); mx.y = fmaxf(mx.y, b.y);
            mx.z = fmaxf(mx.z, b.z); mx.w = fmaxf(mx.w, b.w);
        }
        int cnt = e - s;
        float inv = 1.f / fmaxf((float)cnt, 1.f);
        float4 o;
        o.x = sum.x * inv + mx.x; o.y = sum.y * inv + mx.y;
        o.z = sum.z * inv + mx.z; o.w = sum.w * inv + mx.w;
        *(float4*)&p[(size_t)g * HCDIM + c0] = o;
    }
}

// ============================ Head: logits + softmax ============================
__global__ void logits_kernel(const float* __restrict__ p, const float* __restrict__ Wout,
                              const float* __restrict__ bout, float* __restrict__ out)
{
    __shared__ float red[256];
    __shared__ float lg[NCLS];
    int g = blockIdx.x, t = threadIdx.x;
    float pv = p[g * HCDIM + t];
    for (int j = 0; j < NCLS; ++j) {
        red[t] = pv * Wout[t * NCLS + j];
        __syncthreads();
        for (int off = 128; off > 0; off >>= 1) {
            if (t < off) red[t] += red[t + off];
            __syncthreads();
        }
        if (t == 0) lg[j] = red[0] + bout[j];
        __syncthreads();
    }
    if (t == 0) {
        float mx = fmaxf(lg[0], fmaxf(lg[1], lg[2]));
        float e0 = __expf(lg[0] - mx), e1 = __expf(lg[1] - mx), e2 = __expf(lg[2] - mx);
        float inv = 1.f / (e0 + e1 + e2);
        out[g * NCLS + 0] = e0 * inv;
        out[g * NCLS + 1] = e1 * inv;
        out[g * NCLS + 2] = e2 * inv;
    }
}

// ============================ Orchestration ============================
extern "C" void kernel_launch(void* const* d_in, const int* in_sizes, int n_in,
                              void* d_out, int out_size, void* d_ws, size_t ws_size,
                              hipStream_t stream) {
    const float* x     = (const float*)d_in[0];
    const int*   ei    = (const int*)d_in[1];
    const int*   batch = (const int*)d_in[2];
    const float *Wl[3], *bl[3], *Wr[3], *br[3], *att[3], *bias[3];
    for (int li = 0; li < 3; ++li) {
        int b = 3 + li * 6;
        Wl[li]   = (const float*)d_in[b + 0];
        bl[li]   = (const float*)d_in[b + 1];
        Wr[li]   = (const float*)d_in[b + 2];
        br[li]   = (const float*)d_in[b + 3];
        att[li]  = (const float*)d_in[b + 4];
        bias[li] = (const float*)d_in[b + 5];
    }
    const float* Wout = (const float*)d_in[21];
    const float* bout = (const float*)d_in[22];
    float* out = (float*)d_out;

    size_t off = 0;
    char* wsb = (char*)d_ws;
    auto alloc = [&](size_t bytes) -> char* {
        char* ptr = wsb + off;
        off += (bytes + 255) & ~(size_t)255;
        return ptr;
    };
    int* rowptr  = (int*)alloc((N_NODES + 1) * sizeof(int));
    int* deg     = (int*)alloc(N_NODES * sizeof(int));
    int* cursor  = (int*)alloc(N_NODES * sizeof(int));
    int* colx    = (int*)alloc((size_t)(N_EDGES + N_NODES) * sizeof(int));
    int* startg  = (int*)alloc(NGRAPH * sizeof(int));
    int* endg    = (int*)alloc(NGRAPH * sizeof(int));
    float* xl    = (float*)alloc((size_t)N_NODES * HCDIM * sizeof(float));
    float* xr    = (float*)alloc((size_t)N_NODES * HCDIM * sizeof(float));
    float* hbuf  = (float*)alloc((size_t)N_NODES * HCDIM * sizeof(float));
    float* pbuf  = (float*)alloc((size_t)NGRAPH * HCDIM * sizeof(float));

    hipMemsetAsync(deg, 0, N_NODES * sizeof(int), stream);
    hipMemsetAsync(startg, 0, NGRAPH * sizeof(int), stream);
    hipMemsetAsync(endg, 0, NGRAPH * sizeof(int), stream);

    int tot = N_EDGES + N_NODES;
    hist_kernel<<<(tot + 255) / 256, 256, 0, stream>>>(ei, deg);
    scan_kernel<<<1, 1024, 0, stream>>>(deg, rowptr, cursor);
    fill_kernel<<<(tot + 255) / 256, 256, 0, stream>>>(ei, cursor, colx);
    boundary_kernel<<<(N_NODES + 255) / 256, 256, 0, stream>>>(batch, startg, endg);

    const float* hin = x;
    for (int li = 0; li < 3; ++li) {
        int K = (li == 0) ? F_INPUT : HCDIM;
        gemm_xlxr<<<dim3((N_NODES + 63) / 64, 8), 256, 0, stream>>>(
            hin, K, li > 0 ? 1 : 0, Wl[li], bl[li], Wr[li], br[li], xl, xr);
        gat_edge<<<N_NODES / 4, 256, 0, stream>>>(
            xl, xr, att[li], bias[li], rowptr, colx, hbuf);
        hin = hbuf;
    }

    pool_kernel<<<NGRAPH, 256, 0, stream>>>(hbuf, startg, endg, pbuf);
    logits_kernel<<<NGRAPH, 256, 0, stream>>>(pbuf, Wout, bout, out);
}

// Round 2
// 869.925 us; speedup vs baseline: 1.3551x; 1.3551x over previous
//
#include <hip/hip_runtime.h>
#include <math.h>

#define N_NODES 50000
#define N_EDGES 600000
#define F_INPUT 128
#define HCDIM 256
#define NGRAPH 64
#define NCLS 3
#define MPAD 50048   // 391 * 128, GEMM M padded

typedef __bf16 bf16x8 __attribute__((ext_vector_type(8)));
typedef float f32x4 __attribute__((ext_vector_type(4)));

// ---------------- bf16 split helpers (round-to-nearest-even) ----------------
__device__ __forceinline__ unsigned short f2bf(float f) {
    unsigned int u = __float_as_uint(f);
    u += 0x7fffu + ((u >> 16) & 1u);
    return (unsigned short)(u >> 16);
}
__device__ __forceinline__ float bf2f(unsigned short h) {
    return __uint_as_float((unsigned int)h << 16);
}
__device__ __forceinline__ void split2(float v, unsigned short& hi, unsigned short& lo) {
    hi = f2bf(v);
    lo = f2bf(v - bf2f(hi));
}

__device__ __forceinline__ void gl_lds16(const void* g, void* l) {
    __builtin_amdgcn_global_load_lds(
        (const __attribute__((address_space(1))) unsigned int*)g,
        (__attribute__((address_space(3))) unsigned int*)l, 16, 0, 0);
}

// ============================ CSR build ============================
__global__ void hist_kernel(const int* __restrict__ ei, int* __restrict__ deg) {
    int i = blockIdx.x * 256 + threadIdx.x;
    int total = N_EDGES + N_NODES;
    if (i >= total) return;
    int d = (i < N_EDGES) ? ei[N_EDGES + i] : (i - N_EDGES);
    atomicAdd(&deg[d], 1);
}

__global__ void scan_kernel(const int* __restrict__ deg, int* __restrict__ rowptr,
                            int* __restrict__ cursor) {
    __shared__ int wtot[16];
    __shared__ int carry_s;
    int t = threadIdx.x, lane = t & 63, wid = t >> 6;
    if (t == 0) carry_s = 0;
    __syncthreads();
    for (int base = 0; base < N_NODES; base += 1024) {
        int i = base + t;
        int v = (i < N_NODES) ? deg[i] : 0;
        int x = v;
        #pragma unroll
        for (int off = 1; off < 64; off <<= 1) {
            int y = __shfl_up(x, off, 64);
            if (lane >= off) x += y;
        }
        if (lane == 63) wtot[wid] = x;
        __syncthreads();
        if (wid == 0) {
            int wv = (lane < 16) ? wtot[lane] : 0;
            #pragma unroll
            for (int off = 1; off < 16; off <<= 1) {
                int y = __shfl_up(wv, off, 64);
                if (lane >= off) wv += y;
            }
            if (lane < 16) wtot[lane] = wv;
        }
        __syncthreads();
        int waveoff = (wid > 0) ? wtot[wid - 1] : 0;
        int carry = carry_s;
        if (i < N_NODES) {
            int ex = carry + waveoff + x - v;
            rowptr[i] = ex;
            cursor[i] = ex;
        }
        __syncthreads();
        if (t == 0) carry_s = carry + wtot[15];
        __syncthreads();
    }
    if (t == 0) rowptr[N_NODES] = carry_s;
}

__global__ void fill_kernel(const int* __restrict__ ei, int* __restrict__ cursor,
                            int* __restrict__ colx) {
    int i = blockIdx.x * 256 + threadIdx.x;
    int total = N_EDGES + N_NODES;
    if (i >= total) return;
    int s, d;
    if (i < N_EDGES) { s = ei[i]; d = ei[N_EDGES + i]; }
    else             { s = i - N_EDGES; d = s; }
    int pos = atomicAdd(&cursor[d], 1);
    colx[pos] = s;
}

// ============================ Input split (layer 0 only) ============================
// x fp32 [N,128] -> Xh/Xl bf16 [MPAD,128], pad rows zero.
__global__ void split_x_kernel(const float* __restrict__ src,
                               unsigned short* __restrict__ oh,
                               unsigned short* __restrict__ ol) {
    int idx = blockIdx.x * 256 + threadIdx.x;
    int base = idx * 4;
    if (base >= MPAD * F_INPUT) return;
    int row = base >> 7;   // /128
    float4 v = make_float4(0.f, 0.f, 0.f, 0.f);
    if (row < N_NODES) v = *(const float4*)&src[base];
    ushort4 h, l;
    split2(v.x, h.x, l.x); split2(v.y, h.y, l.y);
    split2(v.z, h.z, l.z); split2(v.w, h.w, l.w);
    *(ushort4*)&oh[base] = h;
    *(ushort4*)&ol[base] = l;
}

// zero the K=256-view pad rows (rows N_NODES..MPAD) of Xh/Xl once per call
__global__ void zero_pad_kernel(unsigned int* __restrict__ a, unsigned int* __restrict__ b) {
    int i = blockIdx.x * 256 + threadIdx.x;
    const int padu = (MPAD - N_NODES) * HCDIM / 2;      // uints
    const int off  = N_NODES * HCDIM / 2;
    if (i < padu) { a[off + i] = 0u; b[off + i] = 0u; }
}

// ============================ Weight split: [Wl|Wr] -> n-major bf16 hi/lo ============================
// W row-major [K][256] each; out Bt[n][k], n in [0,512)
__global__ void split_w_kernel(const float* __restrict__ Wl, const float* __restrict__ Wr,
                               unsigned short* __restrict__ oh, unsigned short* __restrict__ ol,
                               int K) {
    int t = blockIdx.x * 256 + threadIdx.x;
    if (t >= 512 * K) return;
    int n = t & 511, k = t >> 9;
    float w = (n < 256) ? Wl[k * 256 + n] : Wr[k * 256 + (n - 256)];
    unsigned short h, l;
    split2(w, h, l);
    oh[n * K + k] = h;
    ol[n * K + k] = l;
}

// ============================ Split-precision bf16x3 MFMA GEMM ============================
// C[MPAD,512] = X[MPAD,K] @ [Wl|Wr][K,512]; epilogue adds bl/br, writes xl/xr fp32.
// 128x128 tile, BK=32, 4 waves (2x2), each wave 4x4 grid of 16x16x32 MFMA.
__global__ __launch_bounds__(256) void gemm_mfma(
    const unsigned short* __restrict__ Ah, const unsigned short* __restrict__ Al,
    const unsigned short* __restrict__ Bh, const unsigned short* __restrict__ Bl,
    int K,
    const float* __restrict__ bl, const float* __restrict__ br,
    float* __restrict__ xl, float* __restrict__ xr)
{
    __shared__ unsigned short sAh[128 * 32], sAl[128 * 32], sBh[128 * 32], sBl[128 * 32];
    int tid = threadIdx.x;
    int lane = tid & 63, wave = tid >> 6;
    int wm = wave >> 1, wn = wave & 1;
    int row0 = blockIdx.x * 128;
    int n0 = blockIdx.y * 128;
    int quad = lane >> 4, l16 = lane & 15;

    f32x4 acc[4][4];
    #pragma unroll
    for (int i = 0; i < 4; ++i)
        #pragma unroll
        for (int j = 0; j < 4; ++j)
            acc[i][j] = (f32x4){0.f, 0.f, 0.f, 0.f};

    for (int k0 = 0; k0 < K; k0 += 32) {
        __syncthreads();
        #pragma unroll
        for (int pass = 0; pass < 2; ++pass) {
            int c = tid + pass * 256;          // chunk 0..511
            int r = c >> 2, p = (c & 3) * 8;   // tile row, k-elem offset
            size_t ga = (size_t)(row0 + r) * K + k0 + p;
            size_t gb = (size_t)(n0 + r) * K + k0 + p;
            int ld = c * 8;                    // ushort index (16B per chunk)
            gl_lds16(Ah + ga, sAh + ld);
            gl_lds16(Al + ga, sAl + ld);
            gl_lds16(Bh + gb, sBh + ld);
            gl_lds16(Bl + gb, sBl + ld);
        }
        __syncthreads();   // drains vmcnt (global_load_lds) per barrier semantics

        bf16x8 fah[4], fal[4], fbh[4], fbl[4];
        #pragma unroll
        for (int i = 0; i < 4; ++i) {
            int rr = wm * 64 + i * 16 + l16;
            fah[i] = *(const bf16x8*)&sAh[rr * 32 + quad * 8];
            fal[i] = *(const bf16x8*)&sAl[rr * 32 + quad * 8];
            int nn = wn * 64 + i * 16 + l16;
            fbh[i] = *(const bf16x8*)&sBh[nn * 32 + quad * 8];
            fbl[i] = *(const bf16x8*)&sBl[nn * 32 + quad * 8];
        }
        #pragma unroll
        for (int i = 0; i < 4; ++i)
            #pragma unroll
            for (int j = 0; j < 4; ++j) {
                acc[i][j] = __builtin_amdgcn_mfma_f32_16x16x32_bf16(fah[i], fbh[j], acc[i][j], 0, 0, 0);
                acc[i][j] = __builtin_amdgcn_mfma_f32_16x16x32_bf16(fah[i], fbl[j], acc[i][j], 0, 0, 0);
                acc[i][j] = __builtin_amdgcn_mfma_f32_16x16x32_bf16(fal[i], fbh[j], acc[i][j], 0, 0, 0);
            }
    }

    const float* bvec; float* out; int cb0;
    if (blockIdx.y < 2) { out = xl; bvec = bl; cb0 = blockIdx.y * 128; }
    else                { out = xr; bvec = br; cb0 = (blockIdx.y - 2) * 128; }
    #pragma unroll
    for (int j = 0; j < 4; ++j) {
        int col = cb0 + wn * 64 + j * 16 + l16;
        float bj = bvec[col];
        #pragma unroll
        for (int i = 0; i < 4; ++i) {
            int rbase = row0 + wm * 64 + i * 16 + quad * 4;
            #pragma unroll
            for (int r = 0; r < 4; ++r) {
                int row = rbase + r;
                if (row < N_NODES)
                    out[(size_t)row * HCDIM + col] = acc[i][j][r] + bj;
            }
        }
    }
}

// ============================ Edge phase: one wave per dst node, online softmax ============================
// mode 0: write fp32 out (final layer). mode 1: write relu+bf16-split into oh/ol (feeds next GEMM).
__global__ __launch_bounds__(256) void gat_edge(
    const float* __restrict__ xl, const float* __restrict__ xr,
    const float* __restrict__ att, const float* __restrict__ bias,
    const int* __restrict__ rowptr, const int* __restrict__ colx,
    float* __restrict__ out, unsigned short* __restrict__ oh,
    unsigned short* __restrict__ ol, int mode)
{
    int wave = threadIdx.x >> 6;
    int lane = threadIdx.x & 63;
    int node = blockIdx.x * 4 + wave;
    if (node >= N_NODES) return;
    int base = lane * 4;
    float4 xr4 = *(const float4*)&xr[(size_t)node * HCDIM + base];
    float4 at4 = *(const float4*)&att[base];
    int e0 = rowptr[node], e1 = rowptr[node + 1];
    float m = -INFINITY, denom = 0.f;
    float4 acc = make_float4(0.f, 0.f, 0.f, 0.f);
    for (int e = e0; e < e1; ++e) {
        int s = colx[e];
        float4 xs = *(const float4*)&xl[(size_t)s * HCDIM + base];
        float4 v;
        v.x = xs.x + xr4.x; v.y = xs.y + xr4.y; v.z = xs.z + xr4.z; v.w = xs.w + xr4.w;
        v.x = fmaxf(v.x, 0.f) + 0.2f * fminf(v.x, 0.f);
        v.y = fmaxf(v.y, 0.f) + 0.2f * fminf(v.y, 0.f);
        v.z = fmaxf(v.z, 0.f) + 0.2f * fminf(v.z, 0.f);
        v.w = fmaxf(v.w, 0.f) + 0.2f * fminf(v.w, 0.f);
        float p = at4.x * v.x + at4.y * v.y + at4.z * v.z + at4.w * v.w;
        p += __shfl_xor(p, 1, 64);
        p += __shfl_xor(p, 2, 64);
        p += __shfl_xor(p, 4, 64);
        p += __shfl_xor(p, 8, 64);
        float mn = fmaxf(m, p);
        float corr = __expf(m - mn);
        float w = __expf(p - mn);
        acc.x = acc.x * corr + w * xs.x;
        acc.y = acc.y * corr + w * xs.y;
        acc.z = acc.z * corr + w * xs.z;
        acc.w = acc.w * corr + w * xs.w;
        denom = denom * corr + w;
        m = mn;
    }
    float inv = 1.f / denom;
    float4 b4 = *(const float4*)&bias[base];
    float4 o;
    o.x = acc.x * inv + b4.x; o.y = acc.y * inv + b4.y;
    o.z = acc.z * inv + b4.z; o.w = acc.w * inv + b4.w;
    if (mode == 0) {
        *(float4*)&out[(size_t)node * HCDIM + base] = o;
    } else {
        float4 rv;
        rv.x = fmaxf(o.x, 0.f); rv.y = fmaxf(o.y, 0.f);
        rv.z = fmaxf(o.z, 0.f); rv.w = fmaxf(o.w, 0.f);
        ushort4 h, l;
        split2(rv.x, h.x, l.x); split2(rv.y, h.y, l.y);
        split2(rv.z, h.z, l.z); split2(rv.w, h.w, l.w);
        *(ushort4*)&oh[(size_t)node * HCDIM + base] = h;
        *(ushort4*)&ol[(size_t)node * HCDIM + base] = l;
    }
}

// ============================ Pooling ============================
__global__ void boundary_kernel(const int* __restrict__ batch, int* __restrict__ startg,
                                int* __restrict__ endg) {
    int i = blockIdx.x * 256 + threadIdx.x;
    if (i >= N_NODES) return;
    int g = batch[i];
    if (i == 0 || batch[i - 1] != g) startg[g] = i;
    if (i == N_NODES - 1 || batch[i + 1] != g) endg[g] = i + 1;
}

__global__ __launch_bounds__(256) void pool_kernel(
    const float* __restrict__ h, const int* __restrict__ startg,
    const int* __restrict__ endg, float* __restrict__ p)
{
    __shared__ float4 sS[4][64];
    __shared__ float4 sM[4][64];
    int g = blockIdx.x;
    int lane = threadIdx.x & 63;
    int sub = threadIdx.x >> 6;
    int c0 = lane * 4;
    int s = startg[g], e = endg[g];
    float4 sum = make_float4(0.f, 0.f, 0.f, 0.f);
    float4 mx = make_float4(-INFINITY, -INFINITY, -INFINITY, -INFINITY);
    for (int i = s + sub; i < e; i += 4) {
        float4 v = *(const float4*)&h[(size_t)i * HCDIM + c0];
        sum.x += v.x; sum.y += v.y; sum.z += v.z; sum.w += v.w;
        mx.x = fmaxf(mx.x, v.x); mx.y = fmaxf(mx.y, v.y);
        mx.z = fmaxf(mx.z, v.z); mx.w = fmaxf(mx.w, v.w);
    }
    sS[sub][lane] = sum; sM[sub][lane] = mx;
    __syncthreads();
    if (sub == 0) {
        #pragma unroll
        for (int j = 1; j < 4; ++j) {
            float4 a = sS[j][lane], b = sM[j][lane];
            sum.x += a.x; sum.y += a.y; sum.z += a.z; sum.w += a.w;
            mx.x = fmaxf(mx.x, b.x); mx.y = fmaxf(mx.y, b.y);
            mx.z = fmaxf(mx.z, b.z); mx.w = fmaxf(mx.w, b.w);
        }
        int cnt = e - s;
        float inv = 1.f / fmaxf((float)cnt, 1.f);
        float4 o;
        o.x = sum.x * inv + mx.x; o.y = sum.y * inv + mx.y;
        o.z = sum.z * inv + mx.z; o.w = sum.w * inv + mx.w;
        *(float4*)&p[(size_t)g * HCDIM + c0] = o;
    }
}

// ============================ Head: logits + softmax ============================
__global__ void logits_kernel(const float* __restrict__ p, const float* __restrict__ Wout,
                              const float* __restrict__ bout, float* __restrict__ out)
{
    __shared__ float red[256];
    __shared__ float lg[NCLS];
    int g = blockIdx.x, t = threadIdx.x;
    float pv = p[g * HCDIM + t];
    for (int j = 0; j < NCLS; ++j) {
        red[t] = pv * Wout[t * NCLS + j];
        __syncthreads();
        for (int off = 128; off > 0; off >>= 1) {
            if (t < off) red[t] += red[t + off];
            __syncthreads();
        }
        if (t == 0) lg[j] = red[0] + bout[j];
        __syncthreads();
    }
    if (t == 0) {
        float mx = fmaxf(lg[0], fmaxf(lg[1], lg[2]));
        float e0 = __expf(lg[0] - mx), e1 = __expf(lg[1] - mx), e2 = __expf(lg[2] - mx);
        float inv = 1.f / (e0 + e1 + e2);
        out[g * NCLS + 0] = e0 * inv;
        out[g * NCLS + 1] = e1 * inv;
        out[g * NCLS + 2] = e2 * inv;
    }
}

// ============================ Orchestration ============================
extern "C" void kernel_launch(void* const* d_in, const int* in_sizes, int n_in,
                              void* d_out, int out_size, void* d_ws, size_t ws_size,
                              hipStream_t stream) {
    const float* x     = (const float*)d_in[0];
    const int*   ei    = (const int*)d_in[1];
    const int*   batch = (const int*)d_in[2];
    const float *Wl[3], *bl[3], *Wr[3], *br[3], *att[3], *bias[3];
    for (int li = 0; li < 3; ++li) {
        int b = 3 + li * 6;
        Wl[li]   = (const float*)d_in[b + 0];
        bl[li]   = (const float*)d_in[b + 1];
        Wr[li]   = (const float*)d_in[b + 2];
        br[li]   = (const float*)d_in[b + 3];
        att[li]  = (const float*)d_in[b + 4];
        bias[li] = (const float*)d_in[b + 5];
    }
    const float* Wout = (const float*)d_in[21];
    const float* bout = (const float*)d_in[22];
    float* out = (float*)d_out;

    size_t off = 0;
    char* wsb = (char*)d_ws;
    auto alloc = [&](size_t bytes) -> char* {
        char* ptr = wsb + off;
        off += (bytes + 255) & ~(size_t)255;
        return ptr;
    };
    int* rowptr  = (int*)alloc((N_NODES + 1) * sizeof(int));
    int* deg     = (int*)alloc(N_NODES * sizeof(int));
    int* cursor  = (int*)alloc(N_NODES * sizeof(int));
    int* colx    = (int*)alloc((size_t)(N_EDGES + N_NODES) * sizeof(int));
    int* startg  = (int*)alloc(NGRAPH * sizeof(int));
    int* endg    = (int*)alloc(NGRAPH * sizeof(int));
    // Xh and Xl MUST be adjacent: hbuf aliases their combined range at layer 2
    unsigned short* Xh = (unsigned short*)alloc((size_t)MPAD * HCDIM * sizeof(unsigned short));
    unsigned short* Xl = (unsigned short*)alloc((size_t)MPAD * HCDIM * sizeof(unsigned short));
    float* hbuf = (float*)Xh;   // 50000*256*4 B = 51.2 MB <= 2*25.6 MB
    unsigned short* Bth[3];
    unsigned short* Btl[3];
    for (int li = 0; li < 3; ++li) {
        int K = (li == 0) ? F_INPUT : HCDIM;
        Bth[li] = (unsigned short*)alloc((size_t)512 * K * sizeof(unsigned short));
        Btl[li] = (unsigned short*)alloc((size_t)512 * K * sizeof(unsigned short));
    }
    float* xlb = (float*)alloc((size_t)N_NODES * HCDIM * sizeof(float));
    float* xrb = (float*)alloc((size_t)N_NODES * HCDIM * sizeof(float));
    float* pbuf = (float*)alloc((size_t)NGRAPH * HCDIM * sizeof(float));

    hipMemsetAsync(deg, 0, N_NODES * sizeof(int), stream);
    hipMemsetAsync(startg, 0, NGRAPH * sizeof(int), stream);
    hipMemsetAsync(endg, 0, NGRAPH * sizeof(int), stream);

    int tot = N_EDGES + N_NODES;
    hist_kernel<<<(tot + 255) / 256, 256, 0, stream>>>(ei, deg);
    scan_kernel<<<1, 1024, 0, stream>>>(deg, rowptr, cursor);
    fill_kernel<<<(tot + 255) / 256, 256, 0, stream>>>(ei, cursor, colx);
    boundary_kernel<<<(N_NODES + 255) / 256, 256, 0, stream>>>(batch, startg, endg);

    // layer-0 input split + pad zeroing + weight splits
    split_x_kernel<<<(MPAD * F_INPUT / 4 + 255) / 256, 256, 0, stream>>>(x, Xh, Xl);
    zero_pad_kernel<<<((MPAD - N_NODES) * HCDIM / 2 + 255) / 256, 256, 0, stream>>>(
        (unsigned int*)Xh, (unsigned int*)Xl);
    for (int li = 0; li < 3; ++li) {
        int K = (li == 0) ? F_INPUT : HCDIM;
        split_w_kernel<<<(512 * K + 255) / 256, 256, 0, stream>>>(
            Wl[li], Wr[li], Bth[li], Btl[li], K);
    }

    for (int li = 0; li < 3; ++li) {
        int K = (li == 0) ? F_INPUT : HCDIM;
        gemm_mfma<<<dim3(MPAD / 128, 4), 256, 0, stream>>>(
            Xh, Xl, Bth[li], Btl[li], K, bl[li], br[li], xlb, xrb);
        if (li < 2) {
            // write relu + bf16-split for next layer's GEMM (overwrites consumed Xh/Xl)
            gat_edge<<<N_NODES / 4, 256, 0, stream>>>(
                xlb, xrb, att[li], bias[li], rowptr, colx, nullptr, Xh, Xl, 1);
        } else {
            gat_edge<<<N_NODES / 4, 256, 0, stream>>>(
                xlb, xrb, att[li], bias[li], rowptr, colx, hbuf, nullptr, nullptr, 0);
        }
    }

    pool_kernel<<<NGRAPH, 256, 0, stream>>>(hbuf, startg, endg, pbuf);
    logits_kernel<<<NGRAPH, 256, 0, stream>>>(pbuf, Wout, bout, out);
}

// Round 3
// 724.358 us; speedup vs baseline: 1.6275x; 1.2010x over previous
//
#include <hip/hip_runtime.h>
#include <math.h>

#define N_NODES 50000
#define N_EDGES 600000
#define F_INPUT 128
#define HCDIM 256
#define NGRAPH 64
#define NCLS 3
#define MPAD 50048   // 391 * 128, GEMM M padded
#define SCAN_NB ((N_NODES + 255) / 256)   // 196

typedef __bf16 bf16x8 __attribute__((ext_vector_type(8)));
typedef float f32x4 __attribute__((ext_vector_type(4)));
typedef _Float16 f16x4 __attribute__((ext_vector_type(4)));

// ---------------- bf16 split helpers (round-to-nearest-even) ----------------
__device__ __forceinline__ unsigned short f2bf(float f) {
    unsigned int u = __float_as_uint(f);
    u += 0x7fffu + ((u >> 16) & 1u);
    return (unsigned short)(u >> 16);
}
__device__ __forceinline__ float bf2f(unsigned short h) {
    return __uint_as_float((unsigned int)h << 16);
}
__device__ __forceinline__ void split2(float v, unsigned short& hi, unsigned short& lo) {
    hi = f2bf(v);
    lo = f2bf(v - bf2f(hi));
}

__device__ __forceinline__ void gl_lds16(const void* g, void* l) {
    __builtin_amdgcn_global_load_lds(
        (const __attribute__((address_space(1))) unsigned int*)g,
        (__attribute__((address_space(3))) unsigned int*)l, 16, 0, 0);
}

// ============================ CSR build ============================
__global__ void hist_kernel(const int* __restrict__ ei, int* __restrict__ deg) {
    int i = blockIdx.x * 256 + threadIdx.x;
    int total = N_EDGES + N_NODES;
    if (i >= total) return;
    int d = (i < N_EDGES) ? ei[N_EDGES + i] : (i - N_EDGES);
    atomicAdd(&deg[d], 1);
}

// block-local exclusive scan; bsums[b] = block total
__global__ void block_scan_kernel(const int* __restrict__ deg, int* __restrict__ rowptr,
                                  int* __restrict__ bsums) {
    __shared__ int wt[4];
    int b = blockIdx.x, t = threadIdx.x, lane = t & 63, wid = t >> 6;
    int i = b * 256 + t;
    int v = (i < N_NODES) ? deg[i] : 0;
    int x = v;
    #pragma unroll
    for (int off = 1; off < 64; off <<= 1) {
        int y = __shfl_up(x, off, 64);
        if (lane >= off) x += y;
    }
    if (lane == 63) wt[wid] = x;
    __syncthreads();
    if (t == 0) {
        int s = 0;
        #pragma unroll
        for (int j = 0; j < 4; ++j) { int tv = wt[j]; wt[j] = s; s += tv; }
        bsums[b] = s;
    }
    __syncthreads();
    if (i < N_NODES) rowptr[i] = wt[wid] + x - v;
}

// exclusive scan of SCAN_NB block sums (single block)
__global__ void scan_bsums_kernel(int* __restrict__ bsums) {
    __shared__ int wt[4];
    int t = threadIdx.x, lane = t & 63, wid = t >> 6;
    int v = (t < SCAN_NB) ? bsums[t] : 0;
    int x = v;
    #pragma unroll
    for (int off = 1; off < 64; off <<= 1) {
        int y = __shfl_up(x, off, 64);
        if (lane >= off) x += y;
    }
    if (lane == 63) wt[wid] = x;
    __syncthreads();
    if (t == 0) {
        int s = 0;
        #pragma unroll
        for (int j = 0; j < 4; ++j) { int tv = wt[j]; wt[j] = s; s += tv; }
    }
    __syncthreads();
    if (t < SCAN_NB) bsums[t] = wt[wid] + x - v;
}

__global__ void add_off_kernel(int* __restrict__ rowptr, int* __restrict__ cursor,
                               const int* __restrict__ bsums) {
    int i = blockIdx.x * 256 + threadIdx.x;
    if (i < N_NODES) {
        int r = rowptr[i] + bsums[blockIdx.x];
        rowptr[i] = r;
        cursor[i] = r;
    }
    if (i == 0) rowptr[N_NODES] = N_EDGES + N_NODES;
}

__global__ void fill_kernel(const int* __restrict__ ei, int* __restrict__ cursor,
                            int* __restrict__ colx) {
    int i = blockIdx.x * 256 + threadIdx.x;
    int total = N_EDGES + N_NODES;
    if (i >= total) return;
    int s, d;
    if (i < N_EDGES) { s = ei[i]; d = ei[N_EDGES + i]; }
    else             { s = i - N_EDGES; d = s; }
    int pos = atomicAdd(&cursor[d], 1);
    colx[pos] = s;
}

// ============================ Input split (layer 0 only) ============================
__global__ void split_x_kernel(const float* __restrict__ src,
                               unsigned short* __restrict__ oh,
                               unsigned short* __restrict__ ol) {
    int idx = blockIdx.x * 256 + threadIdx.x;
    int base = idx * 4;
    if (base >= MPAD * F_INPUT) return;
    int row = base >> 7;
    float4 v = make_float4(0.f, 0.f, 0.f, 0.f);
    if (row < N_NODES) v = *(const float4*)&src[base];
    ushort4 h, l;
    split2(v.x, h.x, l.x); split2(v.y, h.y, l.y);
    split2(v.z, h.z, l.z); split2(v.w, h.w, l.w);
    *(ushort4*)&oh[base] = h;
    *(ushort4*)&ol[base] = l;
}

__global__ void zero_pad_kernel(unsigned int* __restrict__ a, unsigned int* __restrict__ b) {
    int i = blockIdx.x * 256 + threadIdx.x;
    const int padu = (MPAD - N_NODES) * HCDIM / 2;
    const int off  = N_NODES * HCDIM / 2;
    if (i < padu) { a[off + i] = 0u; b[off + i] = 0u; }
}

// ============================ Weight split ============================
__global__ void split_w_kernel(const float* __restrict__ Wl, const float* __restrict__ Wr,
                               unsigned short* __restrict__ oh, unsigned short* __restrict__ ol,
                               int K) {
    int t = blockIdx.x * 256 + threadIdx.x;
    if (t >= 512 * K) return;
    int n = t & 511, k = t >> 9;
    float w = (n < 256) ? Wl[k * 256 + n] : Wr[k * 256 + (n - 256)];
    unsigned short h, l;
    split2(w, h, l);
    oh[n * K + k] = h;
    ol[n * K + k] = l;
}

// ============================ Split-precision bf16x3 MFMA GEMM ============================
// Grid is 1-D, y-fastest swizzle: 4 consecutive blocks share one A-tile (A HBM read ~1x).
// xl output written as fp16 (halves the edge-phase gather bytes), xr stays fp32.
__global__ __launch_bounds__(256) void gemm_mfma(
    const unsigned short* __restrict__ Ah, const unsigned short* __restrict__ Al,
    const unsigned short* __restrict__ Bh, const unsigned short* __restrict__ Bl,
    int K,
    const float* __restrict__ bl, const float* __restrict__ br,
    _Float16* __restrict__ xlh, float* __restrict__ xr)
{
    __shared__ unsigned short sAh[128 * 32], sAl[128 * 32], sBh[128 * 32], sBl[128 * 32];
    int tid = threadIdx.x;
    int lane = tid & 63, wave = tid >> 6;
    int wm = wave >> 1, wn = wave & 1;
    int bx = blockIdx.x >> 2, by = blockIdx.x & 3;
    int row0 = bx * 128;
    int n0 = by * 128;
    int quad = lane >> 4, l16 = lane & 15;

    f32x4 acc[4][4];
    #pragma unroll
    for (int i = 0; i < 4; ++i)
        #pragma unroll
        for (int j = 0; j < 4; ++j)
            acc[i][j] = (f32x4){0.f, 0.f, 0.f, 0.f};

    for (int k0 = 0; k0 < K; k0 += 32) {
        __syncthreads();
        #pragma unroll
        for (int pass = 0; pass < 2; ++pass) {
            int c = tid + pass * 256;
            int r = c >> 2, p = (c & 3) * 8;
            size_t ga = (size_t)(row0 + r) * K + k0 + p;
            size_t gb = (size_t)(n0 + r) * K + k0 + p;
            int ld = c * 8;
            gl_lds16(Ah + ga, sAh + ld);
            gl_lds16(Al + ga, sAl + ld);
            gl_lds16(Bh + gb, sBh + ld);
            gl_lds16(Bl + gb, sBl + ld);
        }
        __syncthreads();

        bf16x8 fah[4], fal[4], fbh[4], fbl[4];
        #pragma unroll
        for (int i = 0; i < 4; ++i) {
            int rr = wm * 64 + i * 16 + l16;
            fah[i] = *(const bf16x8*)&sAh[rr * 32 + quad * 8];
            fal[i] = *(const bf16x8*)&sAl[rr * 32 + quad * 8];
            int nn = wn * 64 + i * 16 + l16;
            fbh[i] = *(const bf16x8*)&sBh[nn * 32 + quad * 8];
            fbl[i] = *(const bf16x8*)&sBl[nn * 32 + quad * 8];
        }
        #pragma unroll
        for (int i = 0; i < 4; ++i)
            #pragma unroll
            for (int j = 0; j < 4; ++j) {
                acc[i][j] = __builtin_amdgcn_mfma_f32_16x16x32_bf16(fah[i], fbh[j], acc[i][j], 0, 0, 0);
                acc[i][j] = __builtin_amdgcn_mfma_f32_16x16x32_bf16(fah[i], fbl[j], acc[i][j], 0, 0, 0);
                acc[i][j] = __builtin_amdgcn_mfma_f32_16x16x32_bf16(fal[i], fbh[j], acc[i][j], 0, 0, 0);
            }
    }

    if (by < 2) {
        int cb0 = by * 128;
        #pragma unroll
        for (int j = 0; j < 4; ++j) {
            int col = cb0 + wn * 64 + j * 16 + l16;
            float bj = bl[col];
            #pragma unroll
            for (int i = 0; i < 4; ++i) {
                int rbase = row0 + wm * 64 + i * 16 + quad * 4;
                #pragma unroll
                for (int r = 0; r < 4; ++r) {
                    int row = rbase + r;
                    if (row < N_NODES)
                        xlh[(size_t)row * HCDIM + col] = (_Float16)(acc[i][j][r] + bj);
                }
            }
        }
    } else {
        int cb0 = (by - 2) * 128;
        #pragma unroll
        for (int j = 0; j < 4; ++j) {
            int col = cb0 + wn * 64 + j * 16 + l16;
            float bj = br[col];
            #pragma unroll
            for (int i = 0; i < 4; ++i) {
                int rbase = row0 + wm * 64 + i * 16 + quad * 4;
                #pragma unroll
                for (int r = 0; r < 4; ++r) {
                    int row = rbase + r;
                    if (row < N_NODES)
                        xr[(size_t)row * HCDIM + col] = acc[i][j][r] + bj;
                }
            }
        }
    }
}

// ============================ Edge phase: one wave per dst node, online softmax ============================
// xl gathered as fp16 (8B/lane/edge); one-edge software prefetch to hide gather latency.
__global__ __launch_bounds__(256) void gat_edge(
    const _Float16* __restrict__ xlh, const float* __restrict__ xr,
    const float* __restrict__ att, const float* __restrict__ bias,
    const int* __restrict__ rowptr, const int* __restrict__ colx,
    float* __restrict__ out, unsigned short* __restrict__ oh,
    unsigned short* __restrict__ ol, int mode)
{
    int wave = threadIdx.x >> 6;
    int lane = threadIdx.x & 63;
    int node = blockIdx.x * 4 + wave;
    if (node >= N_NODES) return;
    int base = lane * 4;
    float4 xr4 = *(const float4*)&xr[(size_t)node * HCDIM + base];
    float4 at4 = *(const float4*)&att[base];
    int e0 = rowptr[node], e1 = rowptr[node + 1];
    float m = -INFINITY, denom = 0.f;
    float4 acc = make_float4(0.f, 0.f, 0.f, 0.f);
    int scur = colx[e0];
    f16x4 cur = *(const f16x4*)&xlh[(size_t)scur * HCDIM + base];
    for (int e = e0; e < e1; ++e) {
        int sn = (e + 1 < e1) ? colx[e + 1] : scur;
        f16x4 nxt = *(const f16x4*)&xlh[(size_t)sn * HCDIM + base];
        float4 xs;
        xs.x = (float)cur.x; xs.y = (float)cur.y; xs.z = (float)cur.z; xs.w = (float)cur.w;
        float4 v;
        v.x = xs.x + xr4.x; v.y = xs.y + xr4.y; v.z = xs.z + xr4.z; v.w = xs.w + xr4.w;
        v.x = fmaxf(v.x, 0.f) + 0.2f * fminf(v.x, 0.f);
        v.y = fmaxf(v.y, 0.f) + 0.2f * fminf(v.y, 0.f);
        v.z = fmaxf(v.z, 0.f) + 0.2f * fminf(v.z, 0.f);
        v.w = fmaxf(v.w, 0.f) + 0.2f * fminf(v.w, 0.f);
        float p = at4.x * v.x + at4.y * v.y + at4.z * v.z + at4.w * v.w;
        p += __shfl_xor(p, 1, 64);
        p += __shfl_xor(p, 2, 64);
        p += __shfl_xor(p, 4, 64);
        p += __shfl_xor(p, 8, 64);
        float mn = fmaxf(m, p);
        float corr = __expf(m - mn);
        float w = __expf(p - mn);
        acc.x = acc.x * corr + w * xs.x;
        acc.y = acc.y * corr + w * xs.y;
        acc.z = acc.z * corr + w * xs.z;
        acc.w = acc.w * corr + w * xs.w;
        denom = denom * corr + w;
        m = mn;
        cur = nxt;
    }
    float inv = 1.f / denom;
    float4 b4 = *(const float4*)&bias[base];
    float4 o;
    o.x = acc.x * inv + b4.x; o.y = acc.y * inv + b4.y;
    o.z = acc.z * inv + b4.z; o.w = acc.w * inv + b4.w;
    if (mode == 0) {
        *(float4*)&out[(size_t)node * HCDIM + base] = o;
    } else {
        float4 rv;
        rv.x = fmaxf(o.x, 0.f); rv.y = fmaxf(o.y, 0.f);
        rv.z = fmaxf(o.z, 0.f); rv.w = fmaxf(o.w, 0.f);
        ushort4 h, l;
        split2(rv.x, h.x, l.x); split2(rv.y, h.y, l.y);
        split2(rv.z, h.z, l.z); split2(rv.w, h.w, l.w);
        *(ushort4*)&oh[(size_t)node * HCDIM + base] = h;
        *(ushort4*)&ol[(size_t)node * HCDIM + base] = l;
    }
}

// ============================ Pooling ============================
__global__ void boundary_kernel(const int* __restrict__ batch, int* __restrict__ startg,
                                int* __restrict__ endg) {
    int i = blockIdx.x * 256 + threadIdx.x;
    if (i >= N_NODES) return;
    int g = batch[i];
    if (i == 0 || batch[i - 1] != g) startg[g] = i;
    if (i == N_NODES - 1 || batch[i + 1] != g) endg[g] = i + 1;
}

__global__ __launch_bounds__(256) void pool_kernel(
    const float* __restrict__ h, const int* __restrict__ startg,
    const int* __restrict__ endg, float* __restrict__ p)
{
    __shared__ float4 sS[4][64];
    __shared__ float4 sM[4][64];
    int g = blockIdx.x;
    int lane = threadIdx.x & 63;
    int sub = threadIdx.x >> 6;
    int c0 = lane * 4;
    int s = startg[g], e = endg[g];
    float4 sum = make_float4(0.f, 0.f, 0.f, 0.f);
    float4 mx = make_float4(-INFINITY, -INFINITY, -INFINITY, -INFINITY);
    for (int i = s + sub; i < e; i += 4) {
        float4 v = *(const float4*)&h[(size_t)i * HCDIM + c0];
        sum.x += v.x; sum.y += v.y; sum.z += v.z; sum.w += v.w;
        mx.x = fmaxf(mx.x, v.x); mx.y = fmaxf(mx.y, v.y);
        mx.z = fmaxf(mx.z, v.z); mx.w = fmaxf(mx.w, v.w);
    }
    sS[sub][lane] = sum; sM[sub][lane] = mx;
    __syncthreads();
    if (sub == 0) {
        #pragma unroll
        for (int j = 1; j < 4; ++j) {
            float4 a = sS[j][lane], b = sM[j][lane];
            sum.x += a.x; sum.y += a.y; sum.z += a.z; sum.w += a.w;
            mx.x = fmaxf(mx.x, b.x); mx.y = fmaxf(mx.y, b.y);
            mx.z = fmaxf(mx.z, b.z); mx.w = fmaxf(mx.w, b.w);
        }
        int cnt = e - s;
        float inv = 1.f / fmaxf((float)cnt, 1.f);
        float4 o;
        o.x = sum.x * inv + mx.x; o.y = sum.y * inv + mx.y;
        o.z = sum.z * inv + mx.z; o.w = sum.w * inv + mx.w;
        *(float4*)&p[(size_t)g * HCDIM + c0] = o;
    }
}

// ============================ Head: logits + softmax ============================
__global__ void logits_kernel(const float* __restrict__ p, const float* __restrict__ Wout,
                              const float* __restrict__ bout, float* __restrict__ out)
{
    __shared__ float red[256];
    __shared__ float lg[NCLS];
    int g = blockIdx.x, t = threadIdx.x;
    float pv = p[g * HCDIM + t];
    for (int j = 0; j < NCLS; ++j) {
        red[t] = pv * Wout[t * NCLS + j];
        __syncthreads();
        for (int off = 128; off > 0; off >>= 1) {
            if (t < off) red[t] += red[t + off];
            __syncthreads();
        }
        if (t == 0) lg[j] = red[0] + bout[j];
        __syncthreads();
    }
    if (t == 0) {
        float mx = fmaxf(lg[0], fmaxf(lg[1], lg[2]));
        float e0 = __expf(lg[0] - mx), e1 = __expf(lg[1] - mx), e2 = __expf(lg[2] - mx);
        float inv = 1.f / (e0 + e1 + e2);
        out[g * NCLS + 0] = e0 * inv;
        out[g * NCLS + 1] = e1 * inv;
        out[g * NCLS + 2] = e2 * inv;
    }
}

// ============================ Orchestration ============================
extern "C" void kernel_launch(void* const* d_in, const int* in_sizes, int n_in,
                              void* d_out, int out_size, void* d_ws, size_t ws_size,
                              hipStream_t stream) {
    const float* x     = (const float*)d_in[0];
    const int*   ei    = (const int*)d_in[1];
    const int*   batch = (const int*)d_in[2];
    const float *Wl[3], *bl[3], *Wr[3], *br[3], *att[3], *bias[3];
    for (int li = 0; li < 3; ++li) {
        int b = 3 + li * 6;
        Wl[li]   = (const float*)d_in[b + 0];
        bl[li]   = (const float*)d_in[b + 1];
        Wr[li]   = (const float*)d_in[b + 2];
        br[li]   = (const float*)d_in[b + 3];
        att[li]  = (const float*)d_in[b + 4];
        bias[li] = (const float*)d_in[b + 5];
    }
    const float* Wout = (const float*)d_in[21];
    const float* bout = (const float*)d_in[22];
    float* out = (float*)d_out;

    size_t off = 0;
    char* wsb = (char*)d_ws;
    auto alloc = [&](size_t bytes) -> char* {
        char* ptr = wsb + off;
        off += (bytes + 255) & ~(size_t)255;
        return ptr;
    };
    int* rowptr  = (int*)alloc((N_NODES + 1) * sizeof(int));
    int* deg     = (int*)alloc(N_NODES * sizeof(int));
    int* cursor  = (int*)alloc(N_NODES * sizeof(int));
    int* bsums   = (int*)alloc(256 * sizeof(int));
    int* colx    = (int*)alloc((size_t)(N_EDGES + N_NODES) * sizeof(int));
    int* startg  = (int*)alloc(NGRAPH * sizeof(int));
    int* endg    = (int*)alloc(NGRAPH * sizeof(int));
    // Xh and Xl adjacent: hbuf aliases their combined range at the final layer
    unsigned short* Xh = (unsigned short*)alloc((size_t)MPAD * HCDIM * sizeof(unsigned short));
    unsigned short* Xl = (unsigned short*)alloc((size_t)MPAD * HCDIM * sizeof(unsigned short));
    float* hbuf = (float*)Xh;   // 51.2 MB aliases Xh+Xl (both 25.6 MB, adjacent)
    unsigned short* Bth[3];
    unsigned short* Btl[3];
    for (int li = 0; li < 3; ++li) {
        int K = (li == 0) ? F_INPUT : HCDIM;
        Bth[li] = (unsigned short*)alloc((size_t)512 * K * sizeof(unsigned short));
        Btl[li] = (unsigned short*)alloc((size_t)512 * K * sizeof(unsigned short));
    }
    _Float16* xlh = (_Float16*)alloc((size_t)N_NODES * HCDIM * sizeof(_Float16));
    float* xrb    = (float*)alloc((size_t)N_NODES * HCDIM * sizeof(float));
    float* pbuf   = (float*)alloc((size_t)NGRAPH * HCDIM * sizeof(float));

    hipMemsetAsync(deg, 0, N_NODES * sizeof(int), stream);
    hipMemsetAsync(startg, 0, NGRAPH * sizeof(int), stream);
    hipMemsetAsync(endg, 0, NGRAPH * sizeof(int), stream);

    int tot = N_EDGES + N_NODES;
    hist_kernel<<<(tot + 255) / 256, 256, 0, stream>>>(ei, deg);
    block_scan_kernel<<<SCAN_NB, 256, 0, stream>>>(deg, rowptr, bsums);
    scan_bsums_kernel<<<1, 256, 0, stream>>>(bsums);
    add_off_kernel<<<SCAN_NB, 256, 0, stream>>>(rowptr, cursor, bsums);
    fill_kernel<<<(tot + 255) / 256, 256, 0, stream>>>(ei, cursor, colx);
    boundary_kernel<<<(N_NODES + 255) / 256, 256, 0, stream>>>(batch, startg, endg);

    split_x_kernel<<<(MPAD * F_INPUT / 4 + 255) / 256, 256, 0, stream>>>(x, Xh, Xl);
    zero_pad_kernel<<<((MPAD - N_NODES) * HCDIM / 2 + 255) / 256, 256, 0, stream>>>(
        (unsigned int*)Xh, (unsigned int*)Xl);
    for (int li = 0; li < 3; ++li) {
        int K = (li == 0) ? F_INPUT : HCDIM;
        split_w_kernel<<<(512 * K + 255) / 256, 256, 0, stream>>>(
            Wl[li], Wr[li], Bth[li], Btl[li], K);
    }

    for (int li = 0; li < 3; ++li) {
        int K = (li == 0) ? F_INPUT : HCDIM;
        gemm_mfma<<<(MPAD / 128) * 4, 256, 0, stream>>>(
            Xh, Xl, Bth[li], Btl[li], K, bl[li], br[li], xlh, xrb);
        if (li < 2) {
            gat_edge<<<N_NODES / 4, 256, 0, stream>>>(
                xlh, xrb, att[li], bias[li], rowptr, colx, nullptr, Xh, Xl, 1);
        } else {
            gat_edge<<<N_NODES / 4, 256, 0, stream>>>(
                xlh, xrb, att[li], bias[li], rowptr, colx, hbuf, nullptr, nullptr, 0);
        }
    }

    pool_kernel<<<NGRAPH, 256, 0, stream>>>(hbuf, startg, endg, pbuf);
    logits_kernel<<<NGRAPH, 256, 0, stream>>>(pbuf, Wout, bout, out);
}

// Round 4
// 664.426 us; speedup vs baseline: 1.7743x; 1.0902x over previous
//
#include <hip/hip_runtime.h>
#include <math.h>

#define N_NODES 50000
#define N_EDGES 600000
#define F_INPUT 128
#define HCDIM 256
#define NGRAPH 64
#define NCLS 3
#define MPAD 50048   // 391 * 128, GEMM M padded
#define SCAN_NB ((N_NODES + 255) / 256)   // 196

typedef float f32x4 __attribute__((ext_vector_type(4)));
typedef _Float16 f16x8 __attribute__((ext_vector_type(8)));
typedef _Float16 f16x4 __attribute__((ext_vector_type(4)));

__device__ __forceinline__ void gl_lds16(const void* g, void* l) {
    __builtin_amdgcn_global_load_lds(
        (const __attribute__((address_space(1))) unsigned int*)g,
        (__attribute__((address_space(3))) unsigned int*)l, 16, 0, 0);
}

// ============================ CSR build ============================
__global__ void hist_kernel(const int* __restrict__ ei, int* __restrict__ deg) {
    int i = blockIdx.x * 256 + threadIdx.x;
    int total = N_EDGES + N_NODES;
    if (i >= total) return;
    int d = (i < N_EDGES) ? ei[N_EDGES + i] : (i - N_EDGES);
    atomicAdd(&deg[d], 1);
}

__global__ void block_scan_kernel(const int* __restrict__ deg, int* __restrict__ rowptr,
                                  int* __restrict__ bsums) {
    __shared__ int wt[4];
    int b = blockIdx.x, t = threadIdx.x, lane = t & 63, wid = t >> 6;
    int i = b * 256 + t;
    int v = (i < N_NODES) ? deg[i] : 0;
    int x = v;
    #pragma unroll
    for (int off = 1; off < 64; off <<= 1) {
        int y = __shfl_up(x, off, 64);
        if (lane >= off) x += y;
    }
    if (lane == 63) wt[wid] = x;
    __syncthreads();
    if (t == 0) {
        int s = 0;
        #pragma unroll
        for (int j = 0; j < 4; ++j) { int tv = wt[j]; wt[j] = s; s += tv; }
        bsums[b] = s;
    }
    __syncthreads();
    if (i < N_NODES) rowptr[i] = wt[wid] + x - v;
}

__global__ void scan_bsums_kernel(int* __restrict__ bsums) {
    __shared__ int wt[4];
    int t = threadIdx.x, lane = t & 63, wid = t >> 6;
    int v = (t < SCAN_NB) ? bsums[t] : 0;
    int x = v;
    #pragma unroll
    for (int off = 1; off < 64; off <<= 1) {
        int y = __shfl_up(x, off, 64);
        if (lane >= off) x += y;
    }
    if (lane == 63) wt[wid] = x;
    __syncthreads();
    if (t == 0) {
        int s = 0;
        #pragma unroll
        for (int j = 0; j < 4; ++j) { int tv = wt[j]; wt[j] = s; s += tv; }
    }
    __syncthreads();
    if (t < SCAN_NB) bsums[t] = wt[wid] + x - v;
}

__global__ void add_off_kernel(int* __restrict__ rowptr, int* __restrict__ cursor,
                               const int* __restrict__ bsums) {
    int i = blockIdx.x * 256 + threadIdx.x;
    if (i < N_NODES) {
        int r = rowptr[i] + bsums[blockIdx.x];
        rowptr[i] = r;
        cursor[i] = r;
    }
    if (i == 0) rowptr[N_NODES] = N_EDGES + N_NODES;
}

__global__ void fill_kernel(const int* __restrict__ ei, int* __restrict__ cursor,
                            int* __restrict__ colx) {
    int i = blockIdx.x * 256 + threadIdx.x;
    int total = N_EDGES + N_NODES;
    if (i >= total) return;
    int s, d;
    if (i < N_EDGES) { s = ei[i]; d = ei[N_EDGES + i]; }
    else             { s = i - N_EDGES; d = s; }
    int pos = atomicAdd(&cursor[d], 1);
    colx[pos] = s;
}

// ============================ Input convert (layer 0) ============================
// x fp32 [N,128] -> A fp16 [MPAD,128], pad rows zero.
__global__ void split_x_kernel(const float* __restrict__ src, _Float16* __restrict__ A) {
    int idx = blockIdx.x * 256 + threadIdx.x;
    int base = idx * 4;
    if (base >= MPAD * F_INPUT) return;
    int row = base >> 7;
    float4 v = make_float4(0.f, 0.f, 0.f, 0.f);
    if (row < N_NODES) v = *(const float4*)&src[base];
    f16x4 o;
    o.x = (_Float16)v.x; o.y = (_Float16)v.y; o.z = (_Float16)v.z; o.w = (_Float16)v.w;
    *(f16x4*)&A[base] = o;
}

// zero the stride-256 pad rows (rows N_NODES..MPAD) of A for layers 1-2
__global__ void zero_pad_kernel(_Float16* __restrict__ A) {
    int i = blockIdx.x * 256 + threadIdx.x;
    const int padh = (MPAD - N_NODES) * HCDIM;
    if (i * 4 < padh) {
        f16x4 z = {(_Float16)0.f, (_Float16)0.f, (_Float16)0.f, (_Float16)0.f};
        *(f16x4*)&A[(size_t)N_NODES * HCDIM + i * 4] = z;
    }
}

// ============================ Weight split: [Wl|Wr] -> n-major fp16 hi/lo ============================
__global__ void split_w_kernel(const float* __restrict__ Wl, const float* __restrict__ Wr,
                               _Float16* __restrict__ oh, _Float16* __restrict__ ol,
                               int K) {
    int t = blockIdx.x * 256 + threadIdx.x;
    if (t >= 512 * K) return;
    int n = t & 511, k = t >> 9;
    float w = (n < 256) ? Wl[k * 256 + n] : Wr[k * 256 + (n - 256)];
    _Float16 h = (_Float16)w;
    _Float16 l = (_Float16)(w - (float)h);
    oh[n * K + k] = h;
    ol[n * K + k] = l;
}

// ============================ fp16 2-term MFMA GEMM ============================
// C[MPAD,512] = A[MPAD,K] @ (Bh+Bl)[K,512]; A single fp16, B fp16 hi/lo.
// 128x128 tile, BK=32, 4 waves (2x2), each wave 4x4 grid of 16x16x32 f16 MFMA, 2 per acc.
// XOR bank swizzle: global k-chunk p = (c&3)^((r>>1)&3); LDS stays lane-contiguous
// so global_load_lds's identity lane->LDS mapping is preserved (m104 constraint).
__global__ __launch_bounds__(256) void gemm_mfma(
    const _Float16* __restrict__ A,
    const _Float16* __restrict__ Bh, const _Float16* __restrict__ Bl,
    int K,
    const float* __restrict__ bl, const float* __restrict__ br,
    _Float16* __restrict__ xlh, _Float16* __restrict__ xrh)
{
    __shared__ _Float16 sA[128 * 32], sBh[128 * 32], sBl[128 * 32];
    int tid = threadIdx.x;
    int lane = tid & 63, wave = tid >> 6;
    int wm = wave >> 1, wn = wave & 1;
    int bx = blockIdx.x >> 2, by = blockIdx.x & 3;
    int row0 = bx * 128;
    int n0 = by * 128;
    int quad = lane >> 4, l16 = lane & 15;

    f32x4 acc[4][4];
    #pragma unroll
    for (int i = 0; i < 4; ++i)
        #pragma unroll
        for (int j = 0; j < 4; ++j)
            acc[i][j] = (f32x4){0.f, 0.f, 0.f, 0.f};

    for (int k0 = 0; k0 < K; k0 += 32) {
        __syncthreads();
        #pragma unroll
        for (int pass = 0; pass < 2; ++pass) {
            int c = tid + pass * 256;               // chunk 0..511
            int r = c >> 2;
            int p = (c & 3) ^ ((r >> 1) & 3);       // swizzled global k-chunk
            size_t ga = (size_t)(row0 + r) * K + k0 + p * 8;
            size_t gb = (size_t)(n0 + r) * K + k0 + p * 8;
            gl_lds16(A + ga,  sA  + c * 8);
            gl_lds16(Bh + gb, sBh + c * 8);
            gl_lds16(Bl + gb, sBl + c * 8);
        }
        __syncthreads();

        f16x8 fa[4], fbh[4], fbl[4];
        #pragma unroll
        for (int i = 0; i < 4; ++i) {
            int rr = wm * 64 + i * 16 + l16;
            int sa = rr * 4 + (quad ^ ((rr >> 1) & 3));
            fa[i] = *(const f16x8*)&sA[sa * 8];
            int nn = wn * 64 + i * 16 + l16;
            int sb = nn * 4 + (quad ^ ((nn >> 1) & 3));
            fbh[i] = *(const f16x8*)&sBh[sb * 8];
            fbl[i] = *(const f16x8*)&sBl[sb * 8];
        }
        #pragma unroll
        for (int i = 0; i < 4; ++i)
            #pragma unroll
            for (int j = 0; j < 4; ++j) {
                acc[i][j] = __builtin_amdgcn_mfma_f32_16x16x32_f16(fa[i], fbh[j], acc[i][j], 0, 0, 0);
                acc[i][j] = __builtin_amdgcn_mfma_f32_16x16x32_f16(fa[i], fbl[j], acc[i][j], 0, 0, 0);
            }
    }

    _Float16* out; const float* bvec; int cb0;
    if (by < 2) { out = xlh; bvec = bl; cb0 = by * 128; }
    else        { out = xrh; bvec = br; cb0 = (by - 2) * 128; }
    #pragma unroll
    for (int j = 0; j < 4; ++j) {
        int col = cb0 + wn * 64 + j * 16 + l16;
        float bj = bvec[col];
        #pragma unroll
        for (int i = 0; i < 4; ++i) {
            int rbase = row0 + wm * 64 + i * 16 + quad * 4;
            #pragma unroll
            for (int r = 0; r < 4; ++r) {
                int row = rbase + r;
                if (row < N_NODES)
                    out[(size_t)row * HCDIM + col] = (_Float16)(acc[i][j][r] + bj);
            }
        }
    }
}

// ============================ Edge phase: one wave per dst node, online softmax ============================
// mode 0: write fp32 out (final layer). mode 1: write relu'd fp16 activation (next GEMM's A).
__global__ __launch_bounds__(256) void gat_edge(
    const _Float16* __restrict__ xlh, const _Float16* __restrict__ xrh,
    const float* __restrict__ att, const float* __restrict__ bias,
    const int* __restrict__ rowptr, const int* __restrict__ colx,
    float* __restrict__ out, _Float16* __restrict__ onext, int mode)
{
    int wave = threadIdx.x >> 6;
    int lane = threadIdx.x & 63;
    int node = blockIdx.x * 4 + wave;
    if (node >= N_NODES) return;
    int base = lane * 4;
    f16x4 xrh4 = *(const f16x4*)&xrh[(size_t)node * HCDIM + base];
    float4 xr4;
    xr4.x = (float)xrh4.x; xr4.y = (float)xrh4.y; xr4.z = (float)xrh4.z; xr4.w = (float)xrh4.w;
    float4 at4 = *(const float4*)&att[base];
    int e0 = rowptr[node], e1 = rowptr[node + 1];
    float m = -INFINITY, denom = 0.f;
    float4 acc = make_float4(0.f, 0.f, 0.f, 0.f);
    int scur = colx[e0];
    f16x4 cur = *(const f16x4*)&xlh[(size_t)scur * HCDIM + base];
    for (int e = e0; e < e1; ++e) {
        int sn = (e + 1 < e1) ? colx[e + 1] : scur;
        f16x4 nxt = *(const f16x4*)&xlh[(size_t)sn * HCDIM + base];
        float4 xs;
        xs.x = (float)cur.x; xs.y = (float)cur.y; xs.z = (float)cur.z; xs.w = (float)cur.w;
        float4 v;
        v.x = xs.x + xr4.x; v.y = xs.y + xr4.y; v.z = xs.z + xr4.z; v.w = xs.w + xr4.w;
        v.x = fmaxf(v.x, 0.f) + 0.2f * fminf(v.x, 0.f);
        v.y = fmaxf(v.y, 0.f) + 0.2f * fminf(v.y, 0.f);
        v.z = fmaxf(v.z, 0.f) + 0.2f * fminf(v.z, 0.f);
        v.w = fmaxf(v.w, 0.f) + 0.2f * fminf(v.w, 0.f);
        float p = at4.x * v.x + at4.y * v.y + at4.z * v.z + at4.w * v.w;
        p += __shfl_xor(p, 1, 64);
        p += __shfl_xor(p, 2, 64);
        p += __shfl_xor(p, 4, 64);
        p += __shfl_xor(p, 8, 64);
        float mn = fmaxf(m, p);
        float corr = __expf(m - mn);
        float w = __expf(p - mn);
        acc.x = acc.x * corr + w * xs.x;
        acc.y = acc.y * corr + w * xs.y;
        acc.z = acc.z * corr + w * xs.z;
        acc.w = acc.w * corr + w * xs.w;
        denom = denom * corr + w;
        m = mn;
        cur = nxt;
    }
    float inv = 1.f / denom;
    float4 b4 = *(const float4*)&bias[base];
    float4 o;
    o.x = acc.x * inv + b4.x; o.y = acc.y * inv + b4.y;
    o.z = acc.z * inv + b4.z; o.w = acc.w * inv + b4.w;
    if (mode == 0) {
        *(float4*)&out[(size_t)node * HCDIM + base] = o;
    } else {
        f16x4 h;
        h.x = (_Float16)fmaxf(o.x, 0.f); h.y = (_Float16)fmaxf(o.y, 0.f);
        h.z = (_Float16)fmaxf(o.z, 0.f); h.w = (_Float16)fmaxf(o.w, 0.f);
        *(f16x4*)&onext[(size_t)node * HCDIM + base] = h;
    }
}

// ============================ Pooling ============================
__global__ void boundary_kernel(const int* __restrict__ batch, int* __restrict__ startg,
                                int* __restrict__ endg) {
    int i = blockIdx.x * 256 + threadIdx.x;
    if (i >= N_NODES) return;
    int g = batch[i];
    if (i == 0 || batch[i - 1] != g) startg[g] = i;
    if (i == N_NODES - 1 || batch[i + 1] != g) endg[g] = i + 1;
}

__global__ __launch_bounds__(256) void pool_kernel(
    const float* __restrict__ h, const int* __restrict__ startg,
    const int* __restrict__ endg, float* __restrict__ p)
{
    __shared__ float4 sS[4][64];
    __shared__ float4 sM[4][64];
    int g = blockIdx.x;
    int lane = threadIdx.x & 63;
    int sub = threadIdx.x >> 6;
    int c0 = lane * 4;
    int s = startg[g], e = endg[g];
    float4 sum = make_float4(0.f, 0.f, 0.f, 0.f);
    float4 mx = make_float4(-INFINITY, -INFINITY, -INFINITY, -INFINITY);
    for (int i = s + sub; i < e; i += 4) {
        float4 v = *(const float4*)&h[(size_t)i * HCDIM + c0];
        sum.x += v.x; sum.y += v.y; sum.z += v.z; sum.w += v.w;
        mx.x = fmaxf(mx.x, v.x); mx.y = fmaxf(mx.y, v.y);
        mx.z = fmaxf(mx.z, v.z); mx.w = fmaxf(mx.w, v.w);
    }
    sS[sub][lane] = sum; sM[sub][lane] = mx;
    __syncthreads();
    if (sub == 0) {
        #pragma unroll
        for (int j = 1; j < 4; ++j) {
            float4 a = sS[j][lane], b = sM[j][lane];
            sum.x += a.x; sum.y += a.y; sum.z += a.z; sum.w += a.w;
            mx.x = fmaxf(mx.x, b.x); mx.y = fmaxf(mx.y, b.y);
            mx.z = fmaxf(mx.z, b.z); mx.w = fmaxf(mx.w, b.w);
        }
        int cnt = e - s;
        float inv = 1.f / fmaxf((float)cnt, 1.f);
        float4 o;
        o.x = sum.x * inv + mx.x; o.y = sum.y * inv + mx.y;
        o.z = sum.z * inv + mx.z; o.w = sum.w * inv + mx.w;
        *(float4*)&p[(size_t)g * HCDIM + c0] = o;
    }
}

// ============================ Head: logits + softmax ============================
__global__ void logits_kernel(const float* __restrict__ p, const float* __restrict__ Wout,
                              const float* __restrict__ bout, float* __restrict__ out)
{
    __shared__ float red[256];
    __shared__ float lg[NCLS];
    int g = blockIdx.x, t = threadIdx.x;
    float pv = p[g * HCDIM + t];
    for (int j = 0; j < NCLS; ++j) {
        red[t] = pv * Wout[t * NCLS + j];
        __syncthreads();
        for (int off = 128; off > 0; off >>= 1) {
            if (t < off) red[t] += red[t + off];
            __syncthreads();
        }
        if (t == 0) lg[j] = red[0] + bout[j];
        __syncthreads();
    }
    if (t == 0) {
        float mx = fmaxf(lg[0], fmaxf(lg[1], lg[2]));
        float e0 = __expf(lg[0] - mx), e1 = __expf(lg[1] - mx), e2 = __expf(lg[2] - mx);
        float inv = 1.f / (e0 + e1 + e2);
        out[g * NCLS + 0] = e0 * inv;
        out[g * NCLS + 1] = e1 * inv;
        out[g * NCLS + 2] = e2 * inv;
    }
}

// ============================ Orchestration ============================
extern "C" void kernel_launch(void* const* d_in, const int* in_sizes, int n_in,
                              void* d_out, int out_size, void* d_ws, size_t ws_size,
                              hipStream_t stream) {
    const float* x     = (const float*)d_in[0];
    const int*   ei    = (const int*)d_in[1];
    const int*   batch = (const int*)d_in[2];
    const float *Wl[3], *bl[3], *Wr[3], *br[3], *att[3], *bias[3];
    for (int li = 0; li < 3; ++li) {
        int b = 3 + li * 6;
        Wl[li]   = (const float*)d_in[b + 0];
        bl[li]   = (const float*)d_in[b + 1];
        Wr[li]   = (const float*)d_in[b + 2];
        br[li]   = (const float*)d_in[b + 3];
        att[li]  = (const float*)d_in[b + 4];
        bias[li] = (const float*)d_in[b + 5];
    }
    const float* Wout = (const float*)d_in[21];
    const float* bout = (const float*)d_in[22];
    float* out = (float*)d_out;

    size_t off = 0;
    char* wsb = (char*)d_ws;
    auto alloc = [&](size_t bytes) -> char* {
        char* ptr = wsb + off;
        off += (bytes + 255) & ~(size_t)255;
        return ptr;
    };
    int* rowptr  = (int*)alloc((N_NODES + 1) * sizeof(int));
    int* deg     = (int*)alloc(N_NODES * sizeof(int));
    int* cursor  = (int*)alloc(N_NODES * sizeof(int));
    int* bsums   = (int*)alloc(256 * sizeof(int));
    int* colx    = (int*)alloc((size_t)(N_EDGES + N_NODES) * sizeof(int));
    int* startg  = (int*)alloc(NGRAPH * sizeof(int));
    int* endg    = (int*)alloc(NGRAPH * sizeof(int));
    _Float16* Abuf = (_Float16*)alloc((size_t)MPAD * HCDIM * sizeof(_Float16));  // layer0: stride 128 view
    _Float16* Bth[3];
    _Float16* Btl[3];
    for (int li = 0; li < 3; ++li) {
        int K = (li == 0) ? F_INPUT : HCDIM;
        Bth[li] = (_Float16*)alloc((size_t)512 * K * sizeof(_Float16));
        Btl[li] = (_Float16*)alloc((size_t)512 * K * sizeof(_Float16));
    }
    _Float16* xlh = (_Float16*)alloc((size_t)N_NODES * HCDIM * sizeof(_Float16));
    _Float16* xrh = (_Float16*)alloc((size_t)N_NODES * HCDIM * sizeof(_Float16));
    float* hbuf   = (float*)alloc((size_t)N_NODES * HCDIM * sizeof(float));
    float* pbuf   = (float*)alloc((size_t)NGRAPH * HCDIM * sizeof(float));

    hipMemsetAsync(deg, 0, N_NODES * sizeof(int), stream);
    hipMemsetAsync(startg, 0, NGRAPH * sizeof(int), stream);
    hipMemsetAsync(endg, 0, NGRAPH * sizeof(int), stream);

    int tot = N_EDGES + N_NODES;
    hist_kernel<<<(tot + 255) / 256, 256, 0, stream>>>(ei, deg);
    block_scan_kernel<<<SCAN_NB, 256, 0, stream>>>(deg, rowptr, bsums);
    scan_bsums_kernel<<<1, 256, 0, stream>>>(bsums);
    add_off_kernel<<<SCAN_NB, 256, 0, stream>>>(rowptr, cursor, bsums);
    fill_kernel<<<(tot + 255) / 256, 256, 0, stream>>>(ei, cursor, colx);
    boundary_kernel<<<(N_NODES + 255) / 256, 256, 0, stream>>>(batch, startg, endg);

    split_x_kernel<<<(MPAD * F_INPUT / 4 + 255) / 256, 256, 0, stream>>>(x, Abuf);
    zero_pad_kernel<<<((MPAD - N_NODES) * HCDIM / 4 + 255) / 256, 256, 0, stream>>>(Abuf);
    for (int li = 0; li < 3; ++li) {
        int K = (li == 0) ? F_INPUT : HCDIM;
        split_w_kernel<<<(512 * K + 255) / 256, 256, 0, stream>>>(
            Wl[li], Wr[li], Bth[li], Btl[li], K);
    }

    for (int li = 0; li < 3; ++li) {
        int K = (li == 0) ? F_INPUT : HCDIM;
        gemm_mfma<<<(MPAD / 128) * 4, 256, 0, stream>>>(
            Abuf, Bth[li], Btl[li], K, bl[li], br[li], xlh, xrh);
        if (li < 2) {
            gat_edge<<<N_NODES / 4, 256, 0, stream>>>(
                xlh, xrh, att[li], bias[li], rowptr, colx, nullptr, Abuf, 1);
        } else {
            gat_edge<<<N_NODES / 4, 256, 0, stream>>>(
                xlh, xrh, att[li], bias[li], rowptr, colx, hbuf, nullptr, 0);
        }
    }

    pool_kernel<<<NGRAPH, 256, 0, stream>>>(hbuf, startg, endg, pbuf);
    logits_kernel<<<NGRAPH, 256, 0, stream>>>(pbuf, Wout, bout, out);
}

// Round 5
// 644.401 us; speedup vs baseline: 1.8294x; 1.0311x over previous
//
#include <hip/hip_runtime.h>
#include <math.h>

#define N_NODES 50000
#define N_EDGES 600000
#define F_INPUT 128
#define HCDIM 256
#define NGRAPH 64
#define NCLS 3
#define MPAD 50048   // 391 * 128, GEMM M padded
#define SCAN_NB ((N_NODES + 255) / 256)   // 196
#define LOG2E 1.4426950408889634f

typedef float f32x4 __attribute__((ext_vector_type(4)));
typedef _Float16 f16x8 __attribute__((ext_vector_type(8)));
typedef _Float16 f16x4 __attribute__((ext_vector_type(4)));
typedef _Float16 h2 __attribute__((ext_vector_type(2)));

__device__ __forceinline__ void gl_lds16(const void* g, void* l) {
    __builtin_amdgcn_global_load_lds(
        (const __attribute__((address_space(1))) unsigned int*)g,
        (__attribute__((address_space(3))) unsigned int*)l, 16, 0, 0);
}

__device__ __forceinline__ h2 bch2(unsigned int u) { return __builtin_bit_cast(h2, u); }

// packed leaky_relu(0.2): max(v,0) + 0.2*min(v,0)  -> v_pk_max/min/fma
__device__ __forceinline__ h2 lrelu2(h2 v) {
    const h2 z = {(_Float16)0.f, (_Float16)0.f};
    const h2 c = {(_Float16)0.2f, (_Float16)0.2f};
    h2 mx = __builtin_elementwise_max(v, z);
    h2 mn = __builtin_elementwise_min(v, z);
    return mx + mn * c;
}

// ============================ CSR build ============================
__global__ void hist_kernel(const int* __restrict__ ei, int* __restrict__ deg) {
    int i = blockIdx.x * 256 + threadIdx.x;
    int total = N_EDGES + N_NODES;
    if (i >= total) return;
    int d = (i < N_EDGES) ? ei[N_EDGES + i] : (i - N_EDGES);
    atomicAdd(&deg[d], 1);
}

__global__ void block_scan_kernel(const int* __restrict__ deg, int* __restrict__ rowptr,
                                  int* __restrict__ bsums) {
    __shared__ int wt[4];
    int b = blockIdx.x, t = threadIdx.x, lane = t & 63, wid = t >> 6;
    int i = b * 256 + t;
    int v = (i < N_NODES) ? deg[i] : 0;
    int x = v;
    #pragma unroll
    for (int off = 1; off < 64; off <<= 1) {
        int y = __shfl_up(x, off, 64);
        if (lane >= off) x += y;
    }
    if (lane == 63) wt[wid] = x;
    __syncthreads();
    if (t == 0) {
        int s = 0;
        #pragma unroll
        for (int j = 0; j < 4; ++j) { int tv = wt[j]; wt[j] = s; s += tv; }
        bsums[b] = s;
    }
    __syncthreads();
    if (i < N_NODES) rowptr[i] = wt[wid] + x - v;
}

__global__ void scan_bsums_kernel(int* __restrict__ bsums) {
    __shared__ int wt[4];
    int t = threadIdx.x, lane = t & 63, wid = t >> 6;
    int v = (t < SCAN_NB) ? bsums[t] : 0;
    int x = v;
    #pragma unroll
    for (int off = 1; off < 64; off <<= 1) {
        int y = __shfl_up(x, off, 64);
        if (lane >= off) x += y;
    }
    if (lane == 63) wt[wid] = x;
    __syncthreads();
    if (t == 0) {
        int s = 0;
        #pragma unroll
        for (int j = 0; j < 4; ++j) { int tv = wt[j]; wt[j] = s; s += tv; }
    }
    __syncthreads();
    if (t < SCAN_NB) bsums[t] = wt[wid] + x - v;
}

__global__ void add_off_kernel(int* __restrict__ rowptr, int* __restrict__ cursor,
                               const int* __restrict__ bsums) {
    int i = blockIdx.x * 256 + threadIdx.x;
    if (i < N_NODES) {
        int r = rowptr[i] + bsums[blockIdx.x];
        rowptr[i] = r;
        cursor[i] = r;
    }
    if (i == 0) rowptr[N_NODES] = N_EDGES + N_NODES;
}

__global__ void fill_kernel(const int* __restrict__ ei, int* __restrict__ cursor,
                            int* __restrict__ colx) {
    int i = blockIdx.x * 256 + threadIdx.x;
    int total = N_EDGES + N_NODES;
    if (i >= total) return;
    int s, d;
    if (i < N_EDGES) { s = ei[i]; d = ei[N_EDGES + i]; }
    else             { s = i - N_EDGES; d = s; }
    int pos = atomicAdd(&cursor[d], 1);
    colx[pos] = s;
}

// ============================ Input convert (layer 0) ============================
__global__ void split_x_kernel(const float* __restrict__ src, _Float16* __restrict__ A) {
    int idx = blockIdx.x * 256 + threadIdx.x;
    int base = idx * 4;
    if (base >= MPAD * F_INPUT) return;
    int row = base >> 7;
    float4 v = make_float4(0.f, 0.f, 0.f, 0.f);
    if (row < N_NODES) v = *(const float4*)&src[base];
    f16x4 o;
    o.x = (_Float16)v.x; o.y = (_Float16)v.y; o.z = (_Float16)v.z; o.w = (_Float16)v.w;
    *(f16x4*)&A[base] = o;
}

__global__ void zero_pad_kernel(_Float16* __restrict__ A) {
    int i = blockIdx.x * 256 + threadIdx.x;
    const int padh = (MPAD - N_NODES) * HCDIM;
    if (i * 4 < padh) {
        f16x4 z = {(_Float16)0.f, (_Float16)0.f, (_Float16)0.f, (_Float16)0.f};
        *(f16x4*)&A[(size_t)N_NODES * HCDIM + i * 4] = z;
    }
}

// ============================ Weight split: [Wl|Wr] -> n-major fp16 hi/lo ============================
__global__ void split_w_kernel(const float* __restrict__ Wl, const float* __restrict__ Wr,
                               _Float16* __restrict__ oh, _Float16* __restrict__ ol,
                               int K) {
    int t = blockIdx.x * 256 + threadIdx.x;
    if (t >= 512 * K) return;
    int n = t & 511, k = t >> 9;
    float w = (n < 256) ? Wl[k * 256 + n] : Wr[k * 256 + (n - 256)];
    _Float16 h = (_Float16)w;
    _Float16 l = (_Float16)(w - (float)h);
    oh[n * K + k] = h;
    ol[n * K + k] = l;
}

// ============================ fp16 2-term MFMA GEMM ============================
__global__ __launch_bounds__(256) void gemm_mfma(
    const _Float16* __restrict__ A,
    const _Float16* __restrict__ Bh, const _Float16* __restrict__ Bl,
    int K,
    const float* __restrict__ bl, const float* __restrict__ br,
    _Float16* __restrict__ xlh, _Float16* __restrict__ xrh)
{
    __shared__ _Float16 sA[128 * 32], sBh[128 * 32], sBl[128 * 32];
    int tid = threadIdx.x;
    int lane = tid & 63, wave = tid >> 6;
    int wm = wave >> 1, wn = wave & 1;
    int bx = blockIdx.x >> 2, by = blockIdx.x & 3;
    int row0 = bx * 128;
    int n0 = by * 128;
    int quad = lane >> 4, l16 = lane & 15;

    f32x4 acc[4][4];
    #pragma unroll
    for (int i = 0; i < 4; ++i)
        #pragma unroll
        for (int j = 0; j < 4; ++j)
            acc[i][j] = (f32x4){0.f, 0.f, 0.f, 0.f};

    for (int k0 = 0; k0 < K; k0 += 32) {
        __syncthreads();
        #pragma unroll
        for (int pass = 0; pass < 2; ++pass) {
            int c = tid + pass * 256;
            int r = c >> 2;
            int p = (c & 3) ^ ((r >> 1) & 3);
            size_t ga = (size_t)(row0 + r) * K + k0 + p * 8;
            size_t gb = (size_t)(n0 + r) * K + k0 + p * 8;
            gl_lds16(A + ga,  sA  + c * 8);
            gl_lds16(Bh + gb, sBh + c * 8);
            gl_lds16(Bl + gb, sBl + c * 8);
        }
        __syncthreads();

        f16x8 fa[4], fbh[4], fbl[4];
        #pragma unroll
        for (int i = 0; i < 4; ++i) {
            int rr = wm * 64 + i * 16 + l16;
            int sa = rr * 4 + (quad ^ ((rr >> 1) & 3));
            fa[i] = *(const f16x8*)&sA[sa * 8];
            int nn = wn * 64 + i * 16 + l16;
            int sb = nn * 4 + (quad ^ ((nn >> 1) & 3));
            fbh[i] = *(const f16x8*)&sBh[sb * 8];
            fbl[i] = *(const f16x8*)&sBl[sb * 8];
        }
        #pragma unroll
        for (int i = 0; i < 4; ++i)
            #pragma unroll
            for (int j = 0; j < 4; ++j) {
                acc[i][j] = __builtin_amdgcn_mfma_f32_16x16x32_f16(fa[i], fbh[j], acc[i][j], 0, 0, 0);
                acc[i][j] = __builtin_amdgcn_mfma_f32_16x16x32_f16(fa[i], fbl[j], acc[i][j], 0, 0, 0);
            }
    }

    _Float16* out; const float* bvec; int cb0;
    if (by < 2) { out = xlh; bvec = bl; cb0 = by * 128; }
    else        { out = xrh; bvec = br; cb0 = (by - 2) * 128; }
    #pragma unroll
    for (int j = 0; j < 4; ++j) {
        int col = cb0 + wn * 64 + j * 16 + l16;
        float bj = bvec[col];
        #pragma unroll
        for (int i = 0; i < 4; ++i) {
            int rbase = row0 + wm * 64 + i * 16 + quad * 4;
            #pragma unroll
            for (int r = 0; r < 4; ++r) {
                int row = rbase + r;
                if (row < N_NODES)
                    out[(size_t)row * HCDIM + col] = (_Float16)(acc[i][j][r] + bj);
            }
        }
    }
}

// ============================ Edge phase: packed fp16, 2-edge batched online softmax ============================
// lane l: head h=l>>4, channels c0=(l&15)*4..+3 as two fp16x2 pairs. Scores in log2 domain.
__global__ __launch_bounds__(256) void gat_edge(
    const _Float16* __restrict__ xlh, const _Float16* __restrict__ xrh,
    const float* __restrict__ att, const float* __restrict__ bias,
    const int* __restrict__ rowptr, const int* __restrict__ colx,
    float* __restrict__ out, _Float16* __restrict__ onext, int mode)
{
    int wave = threadIdx.x >> 6;
    int lane = threadIdx.x & 63;
    int node = blockIdx.x * 4 + wave;
    if (node >= N_NODES) return;
    int base = lane * 4;

    uint2 xrr = *(const uint2*)&xrh[(size_t)node * HCDIM + base];
    h2 xra = bch2(xrr.x), xrb = bch2(xrr.y);
    float4 at4 = *(const float4*)&att[base];
    h2 ata = {(_Float16)at4.x, (_Float16)at4.y};
    h2 atb = {(_Float16)at4.z, (_Float16)at4.w};

    int e0 = rowptr[node], e1 = rowptr[node + 1];
    float m = -INFINITY, denom = 0.f;
    float4 acc = make_float4(0.f, 0.f, 0.f, 0.f);

    int s0 = colx[e0];
    int s1i = (e0 + 1 < e1) ? e0 + 1 : e0;
    int s1 = colx[s1i];
    uint2 d0 = *(const uint2*)&xlh[(size_t)s0 * HCDIM + base];
    uint2 d1 = *(const uint2*)&xlh[(size_t)s1 * HCDIM + base];

    for (int e = e0; e < e1; e += 2) {
        bool v1 = (e + 1 < e1);
        // prefetch next pair (tail clamps to e1-1: valid, cached)
        int i2 = (e + 2 < e1) ? e + 2 : e1 - 1;
        int i3 = (e + 3 < e1) ? e + 3 : e1 - 1;
        int sn0 = colx[i2], sn1 = colx[i3];
        uint2 nd0 = *(const uint2*)&xlh[(size_t)sn0 * HCDIM + base];
        uint2 nd1 = *(const uint2*)&xlh[(size_t)sn1 * HCDIM + base];

        h2 a0 = bch2(d0.x), b0 = bch2(d0.y);
        h2 a1 = bch2(d1.x), b1 = bch2(d1.y);

        h2 l0a = lrelu2(a0 + xra), l0b = lrelu2(b0 + xrb);
        h2 l1a = lrelu2(a1 + xra), l1b = lrelu2(b1 + xrb);
        float p0 = __builtin_amdgcn_fdot2(l0a, ata, 0.f, false);
        p0 = __builtin_amdgcn_fdot2(l0b, atb, p0, false);
        float p1 = __builtin_amdgcn_fdot2(l1a, ata, 0.f, false);
        p1 = __builtin_amdgcn_fdot2(l1b, atb, p1, false);

        // reduce over the 16 lanes of this head group
        p0 += __shfl_xor(p0, 1, 64);  p1 += __shfl_xor(p1, 1, 64);
        p0 += __shfl_xor(p0, 2, 64);  p1 += __shfl_xor(p1, 2, 64);
        p0 += __shfl_xor(p0, 4, 64);  p1 += __shfl_xor(p1, 4, 64);
        p0 += __shfl_xor(p0, 8, 64);  p1 += __shfl_xor(p1, 8, 64);
        p0 *= LOG2E;
        p1 = v1 ? p1 * LOG2E : -INFINITY;

        float mn = fmaxf(fmaxf(m, p0), p1);
        float corr = exp2f(m - mn);       // exp2f(-inf)=0 handles first iter
        float w0 = exp2f(p0 - mn);
        float w1 = exp2f(p1 - mn);        // 0 when masked
        denom = denom * corr + w0 + w1;
        acc.x = acc.x * corr + w0 * (float)a0.x + w1 * (float)a1.x;
        acc.y = acc.y * corr + w0 * (float)a0.y + w1 * (float)a1.y;
        acc.z = acc.z * corr + w0 * (float)b0.x + w1 * (float)b1.x;
        acc.w = acc.w * corr + w0 * (float)b0.y + w1 * (float)b1.y;
        m = mn;
        d0 = nd0; d1 = nd1;
    }

    float inv = 1.f / denom;
    float4 b4 = *(const float4*)&bias[base];
    float4 o;
    o.x = acc.x * inv + b4.x; o.y = acc.y * inv + b4.y;
    o.z = acc.z * inv + b4.z; o.w = acc.w * inv + b4.w;
    if (mode == 0) {
        *(float4*)&out[(size_t)node * HCDIM + base] = o;
    } else {
        f16x4 h;
        h.x = (_Float16)fmaxf(o.x, 0.f); h.y = (_Float16)fmaxf(o.y, 0.f);
        h.z = (_Float16)fmaxf(o.z, 0.f); h.w = (_Float16)fmaxf(o.w, 0.f);
        *(f16x4*)&onext[(size_t)node * HCDIM + base] = h;
    }
}

// ============================ Pooling ============================
__global__ void boundary_kernel(const int* __restrict__ batch, int* __restrict__ startg,
                                int* __restrict__ endg) {
    int i = blockIdx.x * 256 + threadIdx.x;
    if (i >= N_NODES) return;
    int g = batch[i];
    if (i == 0 || batch[i - 1] != g) startg[g] = i;
    if (i == N_NODES - 1 || batch[i + 1] != g) endg[g] = i + 1;
}

__global__ __launch_bounds__(256) void pool_kernel(
    const float* __restrict__ h, const int* __restrict__ startg,
    const int* __restrict__ endg, float* __restrict__ p)
{
    __shared__ float4 sS[4][64];
    __shared__ float4 sM[4][64];
    int g = blockIdx.x;
    int lane = threadIdx.x & 63;
    int sub = threadIdx.x >> 6;
    int c0 = lane * 4;
    int s = startg[g], e = endg[g];
    float4 sum = make_float4(0.f, 0.f, 0.f, 0.f);
    float4 mx = make_float4(-INFINITY, -INFINITY, -INFINITY, -INFINITY);
    for (int i = s + sub; i < e; i += 4) {
        float4 v = *(const float4*)&h[(size_t)i * HCDIM + c0];
        sum.x += v.x; sum.y += v.y; sum.z += v.z; sum.w += v.w;
        mx.x = fmaxf(mx.x, v.x); mx.y = fmaxf(mx.y, v.y);
        mx.z = fmaxf(mx.z, v.z); mx.w = fmaxf(mx.w, v.w);
    }
    sS[sub][lane] = sum; sM[sub][lane] = mx;
    __syncthreads();
    if (sub == 0) {
        #pragma unroll
        for (int j = 1; j < 4; ++j) {
            float4 a = sS[j][lane], b = sM[j][lane];
            sum.x += a.x; sum.y += a.y; sum.z += a.z; sum.w += a.w;
            mx.x = fmaxf(mx.x, b.x); mx.y = fmaxf(mx.y, b.y);
            mx.z = fmaxf(mx.z, b.z); mx.w = fmaxf(mx.w, b.w);
        }
        int cnt = e - s;
        float inv = 1.f / fmaxf((float)cnt, 1.f);
        float4 o;
        o.x = sum.x * inv + mx.x; o.y = sum.y * inv + mx.y;
        o.z = sum.z * inv + mx.z; o.w = sum.w * inv + mx.w;
        *(float4*)&p[(size_t)g * HCDIM + c0] = o;
    }
}

// ============================ Head: logits + softmax ============================
__global__ void logits_kernel(const float* __restrict__ p, const float* __restrict__ Wout,
                              const float* __restrict__ bout, float* __restrict__ out)
{
    __shared__ float red[256];
    __shared__ float lg[NCLS];
    int g = blockIdx.x, t = threadIdx.x;
    float pv = p[g * HCDIM + t];
    for (int j = 0; j < NCLS; ++j) {
        red[t] = pv * Wout[t * NCLS + j];
        __syncthreads();
        for (int off = 128; off > 0; off >>= 1) {
            if (t < off) red[t] += red[t + off];
            __syncthreads();
        }
        if (t == 0) lg[j] = red[0] + bout[j];
        __syncthreads();
    }
    if (t == 0) {
        float mx = fmaxf(lg[0], fmaxf(lg[1], lg[2]));
        float e0 = __expf(lg[0] - mx), e1 = __expf(lg[1] - mx), e2 = __expf(lg[2] - mx);
        float inv = 1.f / (e0 + e1 + e2);
        out[g * NCLS + 0] = e0 * inv;
        out[g * NCLS + 1] = e1 * inv;
        out[g * NCLS + 2] = e2 * inv;
    }
}

// ============================ Orchestration ============================
extern "C" void kernel_launch(void* const* d_in, const int* in_sizes, int n_in,
                              void* d_out, int out_size, void* d_ws, size_t ws_size,
                              hipStream_t stream) {
    const float* x     = (const float*)d_in[0];
    const int*   ei    = (const int*)d_in[1];
    const int*   batch = (const int*)d_in[2];
    const float *Wl[3], *bl[3], *Wr[3], *br[3], *att[3], *bias[3];
    for (int li = 0; li < 3; ++li) {
        int b = 3 + li * 6;
        Wl[li]   = (const float*)d_in[b + 0];
        bl[li]   = (const float*)d_in[b + 1];
        Wr[li]   = (const float*)d_in[b + 2];
        br[li]   = (const float*)d_in[b + 3];
        att[li]  = (const float*)d_in[b + 4];
        bias[li] = (const float*)d_in[b + 5];
    }
    const float* Wout = (const float*)d_in[21];
    const float* bout = (const float*)d_in[22];
    float* out = (float*)d_out;

    size_t off = 0;
    char* wsb = (char*)d_ws;
    auto alloc = [&](size_t bytes) -> char* {
        char* ptr = wsb + off;
        off += (bytes + 255) & ~(size_t)255;
        return ptr;
    };
    int* rowptr  = (int*)alloc((N_NODES + 1) * sizeof(int));
    int* deg     = (int*)alloc(N_NODES * sizeof(int));
    int* cursor  = (int*)alloc(N_NODES * sizeof(int));
    int* bsums   = (int*)alloc(256 * sizeof(int));
    int* colx    = (int*)alloc((size_t)(N_EDGES + N_NODES) * sizeof(int));
    int* startg  = (int*)alloc(NGRAPH * sizeof(int));
    int* endg    = (int*)alloc(NGRAPH * sizeof(int));
    _Float16* Abuf = (_Float16*)alloc((size_t)MPAD * HCDIM * sizeof(_Float16));
    _Float16* Bth[3];
    _Float16* Btl[3];
    for (int li = 0; li < 3; ++li) {
        int K = (li == 0) ? F_INPUT : HCDIM;
        Bth[li] = (_Float16*)alloc((size_t)512 * K * sizeof(_Float16));
        Btl[li] = (_Float16*)alloc((size_t)512 * K * sizeof(_Float16));
    }
    _Float16* xlh = (_Float16*)alloc((size_t)N_NODES * HCDIM * sizeof(_Float16));
    _Float16* xrh = (_Float16*)alloc((size_t)N_NODES * HCDIM * sizeof(_Float16));
    float* hbuf   = (float*)alloc((size_t)N_NODES * HCDIM * sizeof(float));
    float* pbuf   = (float*)alloc((size_t)NGRAPH * HCDIM * sizeof(float));

    hipMemsetAsync(deg, 0, N_NODES * sizeof(int), stream);
    hipMemsetAsync(startg, 0, NGRAPH * sizeof(int), stream);
    hipMemsetAsync(endg, 0, NGRAPH * sizeof(int), stream);

    int tot = N_EDGES + N_NODES;
    hist_kernel<<<(tot + 255) / 256, 256, 0, stream>>>(ei, deg);
    block_scan_kernel<<<SCAN_NB, 256, 0, stream>>>(deg, rowptr, bsums);
    scan_bsums_kernel<<<1, 256, 0, stream>>>(bsums);
    add_off_kernel<<<SCAN_NB, 256, 0, stream>>>(rowptr, cursor, bsums);
    fill_kernel<<<(tot + 255) / 256, 256, 0, stream>>>(ei, cursor, colx);
    boundary_kernel<<<(N_NODES + 255) / 256, 256, 0, stream>>>(batch, startg, endg);

    split_x_kernel<<<(MPAD * F_INPUT / 4 + 255) / 256, 256, 0, stream>>>(x, Abuf);
    zero_pad_kernel<<<((MPAD - N_NODES) * HCDIM / 4 + 255) / 256, 256, 0, stream>>>(Abuf);
    for (int li = 0; li < 3; ++li) {
        int K = (li == 0) ? F_INPUT : HCDIM;
        split_w_kernel<<<(512 * K + 255) / 256, 256, 0, stream>>>(
            Wl[li], Wr[li], Bth[li], Btl[li], K);
    }

    for (int li = 0; li < 3; ++li) {
        int K = (li == 0) ? F_INPUT : HCDIM;
        gemm_mfma<<<(MPAD / 128) * 4, 256, 0, stream>>>(
            Abuf, Bth[li], Btl[li], K, bl[li], br[li], xlh, xrh);
        if (li < 2) {
            gat_edge<<<N_NODES / 4, 256, 0, stream>>>(
                xlh, xrh, att[li], bias[li], rowptr, colx, nullptr, Abuf, 1);
        } else {
            gat_edge<<<N_NODES / 4, 256, 0, stream>>>(
                xlh, xrh, att[li], bias[li], rowptr, colx, hbuf, nullptr, 0);
        }
    }

    pool_kernel<<<NGRAPH, 256, 0, stream>>>(hbuf, startg, endg, pbuf);
    logits_kernel<<<NGRAPH, 256, 0, stream>>>(pbuf, Wout, bout, out);
}